// Round 5
// baseline (165.865 us; speedup 1.0000x reference)
//
#include <hip/hip_runtime.h>

#define T_LEN 1024
#define EMB   512
#define NH    8
#define HD    64
#define PDIM  32
#define MDIM  4
#define FDIM  128   // PDIM*MDIM
#define TC    64    // chunk length
#define NC    16    // T_LEN/TC

typedef __attribute__((ext_vector_type(8))) short bf16x8;
typedef __attribute__((ext_vector_type(4))) float f32x4;

__device__ __forceinline__ unsigned short f2bf(float f) {
    unsigned u = __float_as_uint(f);
    unsigned r = u + 0x7fffu + ((u >> 16) & 1u);   // RNE
    return (unsigned short)(r >> 16);
}
__device__ __forceinline__ float bf2f(unsigned short h) {
    return __uint_as_float(((unsigned)h) << 16);
}
__device__ __forceinline__ void split4(float4 v, ushort4& h4, ushort4& l4) {
    h4.x = f2bf(v.x); l4.x = f2bf(v.x - bf2f(h4.x));
    h4.y = f2bf(v.y); l4.y = f2bf(v.y - bf2f(h4.y));
    h4.z = f2bf(v.z); l4.z = f2bf(v.z - bf2f(h4.z));
    h4.w = f2bf(v.w); l4.w = f2bf(v.w - bf2f(h4.w));
}
// split-bf16 product: (ah+al)*(bh+bl) ~= ah*bh + ah*bl + al*bh
__device__ __forceinline__ f32x4 mm3(bf16x8 ah, bf16x8 al, bf16x8 bh, bf16x8 bl, f32x4 acc) {
    acc = __builtin_amdgcn_mfma_f32_16x16x32_bf16(ah, bh, acc, 0, 0, 0);
    acc = __builtin_amdgcn_mfma_f32_16x16x32_bf16(ah, bl, acc, 0, 0, 0);
    acc = __builtin_amdgcn_mfma_f32_16x16x32_bf16(al, bh, acc, 0, 0, 0);
    return acc;
}
#define LD8(TILE, ROW, KB) (*reinterpret_cast<const bf16x8*>(&TILE[ROW][KB]))

// ---------------------------------------------------------------------------
// Kernel 1: qkv = x @ qkv_w^T + b. f32 in, on-the-fly hi/lo split, single
// K-pass with 3-combo MFMA. Outputs q,k f32 [H][T][D]; v as Vt hi/lo [H][D][T].
// ---------------------------------------------------------------------------
__global__ __launch_bounds__(256) void k_qkv_mfma(
    const float* __restrict__ X, const float* __restrict__ W,
    const float* __restrict__ bias,
    float* __restrict__ Qh, float* __restrict__ Kh,
    unsigned short* __restrict__ Vthi, unsigned short* __restrict__ Vtlo)
{
    const int j0 = blockIdx.x * 64;   // N=1536
    const int t0 = blockIdx.y * 64;   // M=1024
    __shared__ __align__(16) unsigned short Ahi[64][72], Alo[64][72],
                                            Bhi[64][72], Blo[64][72];
    const int tid = threadIdx.x, lane = tid & 63, wid = tid >> 6;
    const int wrow = (wid >> 1) * 32, wcol = (wid & 1) * 32;
    const int lr = lane & 15, lg = lane >> 4;
    f32x4 acc[2][2];
    #pragma unroll
    for (int i = 0; i < 2; ++i)
        #pragma unroll
        for (int j = 0; j < 2; ++j) acc[i][j] = (f32x4){0.f, 0.f, 0.f, 0.f};

    for (int k0 = 0; k0 < 512; k0 += 64) {
        #pragma unroll
        for (int l = 0; l < 4; ++l) {             // 1024 float4-chunks per tile
            int ch = tid + l * 256;
            int row = ch >> 4, sg = (ch & 15) * 4;
            float4 av = *reinterpret_cast<const float4*>(&X[(size_t)(t0 + row) * 512 + k0 + sg]);
            ushort4 h4, l4; split4(av, h4, l4);
            *reinterpret_cast<ushort4*>(&Ahi[row][sg]) = h4;
            *reinterpret_cast<ushort4*>(&Alo[row][sg]) = l4;
            float4 bv = *reinterpret_cast<const float4*>(&W[(size_t)(j0 + row) * 512 + k0 + sg]);
            split4(bv, h4, l4);
            *reinterpret_cast<ushort4*>(&Bhi[row][sg]) = h4;
            *reinterpret_cast<ushort4*>(&Blo[row][sg]) = l4;
        }
        __syncthreads();
        #pragma unroll
        for (int kh = 0; kh < 2; ++kh) {
            const int kb = kh * 32 + lg * 8;
            bf16x8 ah0 = LD8(Ahi, wrow + lr, kb),      ah1 = LD8(Ahi, wrow + 16 + lr, kb);
            bf16x8 al0 = LD8(Alo, wrow + lr, kb),      al1 = LD8(Alo, wrow + 16 + lr, kb);
            bf16x8 bh0 = LD8(Bhi, wcol + lr, kb),      bh1 = LD8(Bhi, wcol + 16 + lr, kb);
            bf16x8 bl0 = LD8(Blo, wcol + lr, kb),      bl1 = LD8(Blo, wcol + 16 + lr, kb);
            acc[0][0] = mm3(ah0, al0, bh0, bl0, acc[0][0]);
            acc[0][1] = mm3(ah0, al0, bh1, bl1, acc[0][1]);
            acc[1][0] = mm3(ah1, al1, bh0, bl0, acc[1][0]);
            acc[1][1] = mm3(ah1, al1, bh1, bl1, acc[1][1]);
        }
        __syncthreads();
    }
    const int which = j0 >> 9;
    const int h = (j0 & 511) >> 6;
    #pragma unroll
    for (int i = 0; i < 2; ++i)
        #pragma unroll
        for (int j = 0; j < 2; ++j)
            #pragma unroll
            for (int r = 0; r < 4; ++r) {
                int row = wrow + i * 16 + lg * 4 + r;
                int col = wcol + j * 16 + lr;             // = d (j0 % 64 == 0)
                int t = t0 + row, n = j0 + col;
                float val = acc[i][j][r] + bias[n];
                if (which == 0)      Qh[(size_t)(h * T_LEN + t) * HD + col] = val;
                else if (which == 1) Kh[(size_t)(h * T_LEN + t) * HD + col] = val;
                else {
                    unsigned short hv = f2bf(val);
                    size_t vi = (size_t)(h * HD + col) * T_LEN + t;
                    Vthi[vi] = hv; Vtlo[vi] = f2bf(val - bf2f(hv));
                }
            }
}

// ---------------------------------------------------------------------------
// Kernel 6: y = attn @ out_w^T + out_b. A already bf16 hi/lo; W split on fly.
// ---------------------------------------------------------------------------
__global__ __launch_bounds__(256) void k_out_mfma(
    const unsigned short* __restrict__ AThi, const unsigned short* __restrict__ ATlo,
    const float* __restrict__ W, const float* __restrict__ bias,
    float* __restrict__ Y)
{
    const int j0 = blockIdx.x * 64;
    const int t0 = blockIdx.y * 64;
    __shared__ __align__(16) unsigned short Ahi[64][72], Alo[64][72],
                                            Bhi[64][72], Blo[64][72];
    const int tid = threadIdx.x, lane = tid & 63, wid = tid >> 6;
    const int wrow = (wid >> 1) * 32, wcol = (wid & 1) * 32;
    const int lr = lane & 15, lg = lane >> 4;
    f32x4 acc[2][2];
    #pragma unroll
    for (int i = 0; i < 2; ++i)
        #pragma unroll
        for (int j = 0; j < 2; ++j) acc[i][j] = (f32x4){0.f, 0.f, 0.f, 0.f};

    for (int k0 = 0; k0 < 512; k0 += 64) {
        #pragma unroll
        for (int l = 0; l < 2; ++l) {             // A: 512 int4-chunks (bf16)
            int ch = tid + l * 256;
            int row = ch >> 3, sg = (ch & 7) * 8;
            size_t ao = (size_t)(t0 + row) * 512 + k0 + sg;
            *reinterpret_cast<int4*>(&Ahi[row][sg]) = *reinterpret_cast<const int4*>(&AThi[ao]);
            *reinterpret_cast<int4*>(&Alo[row][sg]) = *reinterpret_cast<const int4*>(&ATlo[ao]);
        }
        #pragma unroll
        for (int l = 0; l < 4; ++l) {             // B: f32, split on the fly
            int ch = tid + l * 256;
            int row = ch >> 4, sg = (ch & 15) * 4;
            float4 bv = *reinterpret_cast<const float4*>(&W[(size_t)(j0 + row) * 512 + k0 + sg]);
            ushort4 h4, l4; split4(bv, h4, l4);
            *reinterpret_cast<ushort4*>(&Bhi[row][sg]) = h4;
            *reinterpret_cast<ushort4*>(&Blo[row][sg]) = l4;
        }
        __syncthreads();
        #pragma unroll
        for (int kh = 0; kh < 2; ++kh) {
            const int kb = kh * 32 + lg * 8;
            bf16x8 ah0 = LD8(Ahi, wrow + lr, kb),      ah1 = LD8(Ahi, wrow + 16 + lr, kb);
            bf16x8 al0 = LD8(Alo, wrow + lr, kb),      al1 = LD8(Alo, wrow + 16 + lr, kb);
            bf16x8 bh0 = LD8(Bhi, wcol + lr, kb),      bh1 = LD8(Bhi, wcol + 16 + lr, kb);
            bf16x8 bl0 = LD8(Blo, wcol + lr, kb),      bl1 = LD8(Blo, wcol + 16 + lr, kb);
            acc[0][0] = mm3(ah0, al0, bh0, bl0, acc[0][0]);
            acc[0][1] = mm3(ah0, al0, bh1, bl1, acc[0][1]);
            acc[1][0] = mm3(ah1, al1, bh0, bl0, acc[1][0]);
            acc[1][1] = mm3(ah1, al1, bh1, bl1, acc[1][1]);
        }
        __syncthreads();
    }
    #pragma unroll
    for (int i = 0; i < 2; ++i)
        #pragma unroll
        for (int j = 0; j < 2; ++j)
            #pragma unroll
            for (int r = 0; r < 4; ++r) {
                int row = wrow + i * 16 + lg * 4 + r;
                int col = wcol + j * 16 + lr;
                Y[(size_t)(t0 + row) * EMB + j0 + col] = acc[i][j][r] + bias[j0 + col];
            }
}

// ---------------------------------------------------------------------------
// Kernel 2: features. One block per (h,t); wave0 -> q, wave1 -> k.
// Emits qf/kf hi/lo [H][T][F] and kfT hi/lo [H][F][T].
// ---------------------------------------------------------------------------
__global__ __launch_bounds__(128) void k_features(
    const float* __restrict__ Qh, const float* __restrict__ Kh,
    const float* __restrict__ poly_proj, const float* __restrict__ omega,
    unsigned short* __restrict__ qfhi, unsigned short* __restrict__ qflo,
    unsigned short* __restrict__ kfhi, unsigned short* __restrict__ kflo,
    unsigned short* __restrict__ kfThi, unsigned short* __restrict__ kfTlo)
{
    const int ht = blockIdx.x;          // h*T + t
    const int h = ht >> 10;
    const int t = ht & 1023;
    const int wid = threadIdx.x >> 6, lane = threadIdx.x & 63;
    const float* Z = (wid ? Kh : Qh) + (size_t)ht * HD;
    float z = Z[lane];
    float ss = z * z;
    #pragma unroll
    for (int off = 32; off; off >>= 1) ss += __shfl_xor(ss, off, 64);
    const float inv = 1.0f / fmaxf(sqrtf(ss), 1e-12f);
    __shared__ float zs[2][64];
    __shared__ float poly[2][32];
    __shared__ float prf[2][4];
    zs[wid][lane] = z * inv;
    __syncthreads();
    const float S_NODE = (float)(1.0 / 2.000001);  // matches numpy astype(f32)
    const float SQRT2S = sqrtf(2.0f * S_NODE);
    if (lane < 32) {
        float a = 0.0f;
        for (int d = 0; d < 64; ++d)
            a = fmaf(zs[wid][d], poly_proj[(h * 64 + d) * 32 + lane], a);
        poly[wid][lane] = a * a;
    } else if (lane < 36) {
        const int m = lane - 32;
        float a = 0.0f;
        for (int d = 0; d < 64; ++d)
            a = fmaf(zs[wid][d], omega[(h * 64 + d) * 4 + m], a);
        float arg = fminf(fmaxf(fmaf(a, SQRT2S, -S_NODE), -20.0f), 20.0f);
        prf[wid][m] = expf(arg) * 0.5f;   // / sqrt(M=4)
    }
    __syncthreads();
    #pragma unroll
    for (int r = 0; r < 2; ++r) {
        int f = lane * 2 + r;
        float val = poly[wid][f >> 2] * prf[wid][f & 3];
        unsigned short hv = f2bf(val), lv = f2bf(val - bf2f(hv));
        size_t fi = (size_t)ht * FDIM + f;
        if (wid == 0) { qfhi[fi] = hv; qflo[fi] = lv; }
        else {
            kfhi[fi] = hv; kflo[fi] = lv;
            size_t ti = (size_t)(h * FDIM + f) * T_LEN + t;
            kfThi[ti] = hv; kfTlo[ti] = lv;
        }
    }
}

// ---------------------------------------------------------------------------
// Kernel 3: per-chunk S_c[f][d] = sum_t kf[t][f]*v[t][d] via MFMA.
// A-op = kfT[f][t] hi/lo, B-op = Vt[d][t] hi/lo. M=128, N=64, K=64.
// ---------------------------------------------------------------------------
__global__ __launch_bounds__(256) void k_chunk_kv(
    const unsigned short* __restrict__ kfThi, const unsigned short* __restrict__ kfTlo,
    const unsigned short* __restrict__ Vthi, const unsigned short* __restrict__ Vtlo,
    float* __restrict__ Sch, float* __restrict__ zch)
{
    const int b = blockIdx.x, h = b >> 4, c = b & 15;
    const int t0 = c * TC;
    const int tid = threadIdx.x, lane = tid & 63, wid = tid >> 6;
    const int wrow = (wid >> 1) * 64, wcol = (wid & 1) * 32;
    const int lr = lane & 15, lg = lane >> 4;
    __shared__ __align__(16) unsigned short Ahi[128][72], Alo[128][72],
                                            Bhi[64][72], Blo[64][72];
    #pragma unroll
    for (int l = 0; l < 4; ++l) {                 // A: 1024 int4-chunks
        int ch = tid + l * 256;
        int f = ch >> 3, sg = (ch & 7) * 8;
        size_t ao = (size_t)(h * FDIM + f) * T_LEN + t0 + sg;
        *reinterpret_cast<int4*>(&Ahi[f][sg]) = *reinterpret_cast<const int4*>(&kfThi[ao]);
        *reinterpret_cast<int4*>(&Alo[f][sg]) = *reinterpret_cast<const int4*>(&kfTlo[ao]);
    }
    #pragma unroll
    for (int l = 0; l < 2; ++l) {                 // B: 512 int4-chunks
        int ch = tid + l * 256;
        int d = ch >> 3, sg = (ch & 7) * 8;
        size_t vo = (size_t)(h * HD + d) * T_LEN + t0 + sg;
        *reinterpret_cast<int4*>(&Bhi[d][sg]) = *reinterpret_cast<const int4*>(&Vthi[vo]);
        *reinterpret_cast<int4*>(&Blo[d][sg]) = *reinterpret_cast<const int4*>(&Vtlo[vo]);
    }
    __syncthreads();
    f32x4 acc[4][2];
    #pragma unroll
    for (int i = 0; i < 4; ++i)
        #pragma unroll
        for (int j = 0; j < 2; ++j) acc[i][j] = (f32x4){0.f, 0.f, 0.f, 0.f};
    #pragma unroll
    for (int kh = 0; kh < 2; ++kh) {
        const int kb = kh * 32 + lg * 8;
        bf16x8 bh0 = LD8(Bhi, wcol + lr, kb),      bh1 = LD8(Bhi, wcol + 16 + lr, kb);
        bf16x8 bl0 = LD8(Blo, wcol + lr, kb),      bl1 = LD8(Blo, wcol + 16 + lr, kb);
        #pragma unroll
        for (int fi = 0; fi < 4; ++fi) {
            bf16x8 ah = LD8(Ahi, wrow + fi * 16 + lr, kb);
            bf16x8 al = LD8(Alo, wrow + fi * 16 + lr, kb);
            acc[fi][0] = mm3(ah, al, bh0, bl0, acc[fi][0]);
            acc[fi][1] = mm3(ah, al, bh1, bl1, acc[fi][1]);
        }
    }
    if (tid < FDIM) {
        float s = 0.f;
        for (int tt = 0; tt < TC; ++tt) s += bf2f(Ahi[tid][tt]) + bf2f(Alo[tid][tt]);
        zch[(h * NC + c) * FDIM + tid] = s;
    }
    float* S = Sch + (size_t)(h * NC + c) * FDIM * HD;
    #pragma unroll
    for (int fi = 0; fi < 4; ++fi)
        #pragma unroll
        for (int dj = 0; dj < 2; ++dj)
            #pragma unroll
            for (int r = 0; r < 4; ++r) {
                int f = wrow + fi * 16 + lg * 4 + r;
                int d = wcol + dj * 16 + lr;
                S[f * HD + d] = acc[fi][dj][r];
            }
}

// ---------------------------------------------------------------------------
// Kernel 4: exclusive prefix over chunks; emits SpreT hi/lo [H][NC][D][F]
// (transposed + split for attn's B-operand) and zpre f32.
// ---------------------------------------------------------------------------
__global__ __launch_bounds__(256) void k_prefix(
    const float* __restrict__ Sch, const float* __restrict__ zch,
    unsigned short* __restrict__ SThi, unsigned short* __restrict__ STlo,
    float* __restrict__ zpre)
{
    const int h = blockIdx.x >> 5;
    const int e = ((blockIdx.x & 31) << 8) + threadIdx.x;   // f*64+d
    const int f = e >> 6, d = e & 63;
    const size_t rbase = (size_t)h * NC * FDIM * HD + e;
    float vals[NC];
    #pragma unroll
    for (int c = 0; c < NC; ++c) vals[c] = Sch[rbase + (size_t)c * FDIM * HD];
    float run = 0.0f;
    #pragma unroll
    for (int c = 0; c < NC; ++c) {
        size_t wi = (size_t)((h * NC + c) * HD + d) * FDIM + f;
        unsigned short hv = f2bf(run);
        SThi[wi] = hv; STlo[wi] = f2bf(run - bf2f(hv));
        run += vals[c];
    }
    if ((blockIdx.x & 31) == 0 && threadIdx.x < FDIM) {
        const int zb = h * NC * FDIM + threadIdx.x;
        float zv[NC];
        #pragma unroll
        for (int c = 0; c < NC; ++c) zv[c] = zch[zb + c * FDIM];
        float zr = 0.0f;
        #pragma unroll
        for (int c = 0; c < NC; ++c) { zpre[zb + c * FDIM] = zr; zr += zv[c]; }
    }
}

// ---------------------------------------------------------------------------
// Kernel 5: attention core, all-MFMA.
//   phase1 (f-sliced): accA = Qf.Kf^T, accC = Qf.Spre; nint = qf.zpre (VALU)
//   phase2: mask accA, rowsum -> norm_intra; masked A -> LDS bf16 hi/lo
//   phase3: accC += A.V (B-op = Vt)
//   epilogue: out = accC / max(norm,1e-6) -> AT hi/lo [T][EMB]
// ---------------------------------------------------------------------------
__global__ __launch_bounds__(256) void k_attn_mfma(
    const unsigned short* __restrict__ qfhi, const unsigned short* __restrict__ qflo,
    const unsigned short* __restrict__ kfhi, const unsigned short* __restrict__ kflo,
    const unsigned short* __restrict__ SThi, const unsigned short* __restrict__ STlo,
    const unsigned short* __restrict__ Vthi, const unsigned short* __restrict__ Vtlo,
    const float* __restrict__ zpre,
    unsigned short* __restrict__ AThi, unsigned short* __restrict__ ATlo)
{
    const int b = blockIdx.x, h = b >> 4, c = b & 15;
    const int t0 = c * TC;
    const int tid = threadIdx.x, lane = tid & 63, wid = tid >> 6;
    const int wrow = (wid >> 1) * 32, wcol = (wid & 1) * 32;
    const int lr = lane & 15, lg = lane >> 4;

    // tiles: phase1 {T0,T1}=qf hi/lo, {T2,T3}=kf hi/lo, {T4,T5}=SpreT hi/lo
    //        phase3 {T0,T1}=masked A hi/lo, {T2,T3}=Vt hi/lo
    __shared__ __align__(16) unsigned short T0[64][72], T1[64][72], T2[64][72],
                                            T3[64][72], T4[64][72], T5[64][72];
    __shared__ float zpre_s[FDIM], nrm_part[2][TC], nint_s[TC], nrm[TC];

    if (tid < FDIM) zpre_s[tid] = zpre[(h * NC + c) * FDIM + tid];

    f32x4 accA[2][2], accC[2][2];
    #pragma unroll
    for (int i = 0; i < 2; ++i)
        #pragma unroll
        for (int j = 0; j < 2; ++j) {
            accA[i][j] = (f32x4){0.f, 0.f, 0.f, 0.f};
            accC[i][j] = (f32x4){0.f, 0.f, 0.f, 0.f};
        }
    float nint = 0.f;

    for (int f0 = 0; f0 < FDIM; f0 += 64) {
        #pragma unroll
        for (int l = 0; l < 2; ++l) {             // 512 int4-chunks per tile
            int ch = tid + l * 256;
            int row = ch >> 3, sg = (ch & 7) * 8;
            size_t qo = (size_t)(h * T_LEN + t0 + row) * FDIM + f0 + sg;
            *reinterpret_cast<int4*>(&T0[row][sg]) = *reinterpret_cast<const int4*>(&qfhi[qo]);
            *reinterpret_cast<int4*>(&T1[row][sg]) = *reinterpret_cast<const int4*>(&qflo[qo]);
            *reinterpret_cast<int4*>(&T2[row][sg]) = *reinterpret_cast<const int4*>(&kfhi[qo]);
            *reinterpret_cast<int4*>(&T3[row][sg]) = *reinterpret_cast<const int4*>(&kflo[qo]);
            size_t so = (size_t)((h * NC + c) * HD + row) * FDIM + f0 + sg;
            *reinterpret_cast<int4*>(&T4[row][sg]) = *reinterpret_cast<const int4*>(&SThi[so]);
            *reinterpret_cast<int4*>(&T5[row][sg]) = *reinterpret_cast<const int4*>(&STlo[so]);
        }
        __syncthreads();
        #pragma unroll
        for (int kh = 0; kh < 2; ++kh) {
            const int kb = kh * 32 + lg * 8;
            bf16x8 qh0 = LD8(T0, wrow + lr, kb),      qh1 = LD8(T0, wrow + 16 + lr, kb);
            bf16x8 ql0 = LD8(T1, wrow + lr, kb),      ql1 = LD8(T1, wrow + 16 + lr, kb);
            bf16x8 kh0 = LD8(T2, wcol + lr, kb),      kh1 = LD8(T2, wcol + 16 + lr, kb);
            bf16x8 kl0 = LD8(T3, wcol + lr, kb),      kl1 = LD8(T3, wcol + 16 + lr, kb);
            bf16x8 sh0 = LD8(T4, wcol + lr, kb),      sh1 = LD8(T4, wcol + 16 + lr, kb);
            bf16x8 sl0 = LD8(T5, wcol + lr, kb),      sl1 = LD8(T5, wcol + 16 + lr, kb);
            accA[0][0] = mm3(qh0, ql0, kh0, kl0, accA[0][0]);
            accA[0][1] = mm3(qh0, ql0, kh1, kl1, accA[0][1]);
            accA[1][0] = mm3(qh1, ql1, kh0, kl0, accA[1][0]);
            accA[1][1] = mm3(qh1, ql1, kh1, kl1, accA[1][1]);
            accC[0][0] = mm3(qh0, ql0, sh0, sl0, accC[0][0]);
            accC[0][1] = mm3(qh0, ql0, sh1, sl1, accC[0][1]);
            accC[1][0] = mm3(qh1, ql1, sh0, sl0, accC[1][0]);
            accC[1][1] = mm3(qh1, ql1, sh1, sl1, accC[1][1]);
        }
        if (tid < TC) {
            for (int ff = 0; ff < 64; ++ff)
                nint = fmaf(bf2f(T0[tid][ff]) + bf2f(T1[tid][ff]), zpre_s[f0 + ff], nint);
        }
        __syncthreads();
    }

    // ---- phase 2: mask + rowsum + write A (bf16 hi/lo) into T0/T1 ----
    #pragma unroll
    for (int i = 0; i < 2; ++i) {
        #pragma unroll
        for (int r = 0; r < 4; ++r) {
            int row = wrow + i * 16 + lg * 4 + r;
            float rs = 0.f;
            #pragma unroll
            for (int j = 0; j < 2; ++j) {
                int col = wcol + j * 16 + lr;
                float v = (col <= row) ? accA[i][j][r] : 0.f;
                rs += v;
                unsigned short hv = f2bf(v);
                T0[row][col] = hv;
                T1[row][col] = f2bf(v - bf2f(hv));
            }
            #pragma unroll
            for (int off = 1; off < 16; off <<= 1) rs += __shfl_xor(rs, off, 64);
            if (lr == 0) nrm_part[wid & 1][row] = rs;
        }
    }
    if (tid < TC) nint_s[tid] = nint;
    #pragma unroll
    for (int l = 0; l < 2; ++l) {                 // stage Vt into T2/T3
        int ch = tid + l * 256;
        int row = ch >> 3, sg = (ch & 7) * 8;
        size_t vo = (size_t)(h * HD + row) * T_LEN + t0 + sg;
        *reinterpret_cast<int4*>(&T2[row][sg]) = *reinterpret_cast<const int4*>(&Vthi[vo]);
        *reinterpret_cast<int4*>(&T3[row][sg]) = *reinterpret_cast<const int4*>(&Vtlo[vo]);
    }
    __syncthreads();
    if (tid < TC)
        nrm[tid] = fmaxf(nrm_part[0][tid] + nrm_part[1][tid] + nint_s[tid], 1e-6f);

    // ---- phase 3: accC += A_masked @ V ----
    #pragma unroll
    for (int kh = 0; kh < 2; ++kh) {
        const int kb = kh * 32 + lg * 8;
        bf16x8 ah0 = LD8(T0, wrow + lr, kb),      ah1 = LD8(T0, wrow + 16 + lr, kb);
        bf16x8 al0 = LD8(T1, wrow + lr, kb),      al1 = LD8(T1, wrow + 16 + lr, kb);
        bf16x8 bh0 = LD8(T2, wcol + lr, kb),      bh1 = LD8(T2, wcol + 16 + lr, kb);
        bf16x8 bl0 = LD8(T3, wcol + lr, kb),      bl1 = LD8(T3, wcol + 16 + lr, kb);
        accC[0][0] = mm3(ah0, al0, bh0, bl0, accC[0][0]);
        accC[0][1] = mm3(ah0, al0, bh1, bl1, accC[0][1]);
        accC[1][0] = mm3(ah1, al1, bh0, bl0, accC[1][0]);
        accC[1][1] = mm3(ah1, al1, bh1, bl1, accC[1][1]);
    }
    __syncthreads();

    #pragma unroll
    for (int i = 0; i < 2; ++i)
        #pragma unroll
        for (int j = 0; j < 2; ++j)
            #pragma unroll
            for (int r = 0; r < 4; ++r) {
                int row = wrow + i * 16 + lg * 4 + r;
                int col = wcol + j * 16 + lr;
                float o = accC[i][j][r] / nrm[row];
                unsigned short hv = f2bf(o);
                size_t oi = (size_t)(t0 + row) * EMB + h * HD + col;
                AThi[oi] = hv; ATlo[oi] = f2bf(o - bf2f(hv));
            }
}

// ---------------------------------------------------------------------------
// Workspace (22.1 MB), overlays verified against launch order:
//   AThi/ATlo  in q's space   (q: w@qkv, r@features; AT: w@attn, r@out)
//   SThi/STlo  in kfT's space (kfT: w@features, r@chunk_kv; ST: w@prefix, r@attn)
// ---------------------------------------------------------------------------
extern "C" void kernel_launch(void* const* d_in, const int* in_sizes, int n_in,
                              void* d_out, int out_size, void* d_ws, size_t ws_size,
                              hipStream_t stream) {
    const float* x         = (const float*)d_in[0];
    const float* qkv_w     = (const float*)d_in[1];
    const float* qkv_b     = (const float*)d_in[2];
    const float* out_w     = (const float*)d_in[3];
    const float* out_b     = (const float*)d_in[4];
    const float* omega     = (const float*)d_in[5];
    const float* poly_proj = (const float*)d_in[6];
    float* out = (float*)d_out;

    float* ws = (float*)d_ws;
    float* q = ws;                                           // 524288 f32
    float* k = q + 524288;                                   // 524288 f32
    unsigned short* Vthi  = (unsigned short*)(k + 524288);   // 524288 u16
    unsigned short* Vtlo  = Vthi + 524288;
    unsigned short* qfhi  = Vtlo + 524288;                   // 1048576 u16 each
    unsigned short* qflo  = qfhi + 1048576;
    unsigned short* kfhi  = qflo + 1048576;
    unsigned short* kflo  = kfhi + 1048576;
    unsigned short* kfThi = kflo + 1048576;
    unsigned short* kfTlo = kfThi + 1048576;
    float* Sch  = (float*)(kfTlo + 1048576);                 // 1048576 f32
    float* zch  = Sch + 1048576;                             // 16384
    float* zpre = zch + 16384;                               // 16384
    unsigned short* SThi = kfThi;                            // overlay
    unsigned short* STlo = kfTlo;
    unsigned short* AThi = (unsigned short*)q;               // overlay
    unsigned short* ATlo = AThi + 524288;

    k_qkv_mfma<<<dim3(24, 16), 256, 0, stream>>>(x, qkv_w, qkv_b, q, k, Vthi, Vtlo);
    k_features<<<NH * T_LEN, 128, 0, stream>>>(q, k, poly_proj, omega,
                                               qfhi, qflo, kfhi, kflo, kfThi, kfTlo);
    k_chunk_kv<<<NH * NC, 256, 0, stream>>>(kfThi, kfTlo, Vthi, Vtlo, Sch, zch);
    k_prefix<<<256, 256, 0, stream>>>(Sch, zch, SThi, STlo, zpre);
    k_attn_mfma<<<NH * NC, 256, 0, stream>>>(qfhi, qflo, kfhi, kflo, SThi, STlo,
                                             Vthi, Vtlo, zpre, AThi, ATlo);
    k_out_mfma<<<dim3(8, 16), 256, 0, stream>>>(AThi, ATlo, out_w, out_b, out);
}

// Round 6
// 140.496 us; speedup vs baseline: 1.1806x; 1.1806x over previous
//
#include <hip/hip_runtime.h>

#define T_LEN 1024
#define EMB   512
#define NH    8
#define HD    64
#define PDIM  32
#define MDIM  4
#define FDIM  128   // PDIM*MDIM
#define TC    64    // chunk length
#define NC    16    // T_LEN/TC

typedef __attribute__((ext_vector_type(8))) short bf16x8;
typedef __attribute__((ext_vector_type(4))) float f32x4;

__device__ __forceinline__ unsigned short f2bf(float f) {
    unsigned u = __float_as_uint(f);
    unsigned r = u + 0x7fffu + ((u >> 16) & 1u);   // RNE
    return (unsigned short)(r >> 16);
}
__device__ __forceinline__ float bf2f(unsigned short h) {
    return __uint_as_float(((unsigned)h) << 16);
}
__device__ __forceinline__ void split4(float4 v, ushort4& h4, ushort4& l4) {
    h4.x = f2bf(v.x); l4.x = f2bf(v.x - bf2f(h4.x));
    h4.y = f2bf(v.y); l4.y = f2bf(v.y - bf2f(h4.y));
    h4.z = f2bf(v.z); l4.z = f2bf(v.z - bf2f(h4.z));
    h4.w = f2bf(v.w); l4.w = f2bf(v.w - bf2f(h4.w));
}
// split-bf16 product: (ah+al)*(bh+bl) ~= ah*bh + ah*bl + al*bh
__device__ __forceinline__ f32x4 mm3(bf16x8 ah, bf16x8 al, bf16x8 bh, bf16x8 bl, f32x4 acc) {
    acc = __builtin_amdgcn_mfma_f32_16x16x32_bf16(ah, bh, acc, 0, 0, 0);
    acc = __builtin_amdgcn_mfma_f32_16x16x32_bf16(ah, bl, acc, 0, 0, 0);
    acc = __builtin_amdgcn_mfma_f32_16x16x32_bf16(al, bh, acc, 0, 0, 0);
    return acc;
}
#define LD8(TILE, ROW, KB) (*reinterpret_cast<const bf16x8*>(&TILE[ROW][KB]))

// ---------------------------------------------------------------------------
// Kernel 1: qkv = x @ qkv_w^T + b. On-the-fly hi/lo split in staging,
// single K-pass, 3-combo MFMA. Outputs q,k,v all f32 [H][T][D] (coalesced).
// ---------------------------------------------------------------------------
__global__ __launch_bounds__(256) void k_qkv_mfma(
    const float* __restrict__ X, const float* __restrict__ W,
    const float* __restrict__ bias,
    float* __restrict__ Qh, float* __restrict__ Kh, float* __restrict__ Vh)
{
    const int j0 = blockIdx.x * 64;   // N=1536
    const int t0 = blockIdx.y * 64;   // M=1024
    __shared__ __align__(16) unsigned short Ahi[64][72], Alo[64][72],
                                            Bhi[64][72], Blo[64][72];
    const int tid = threadIdx.x, lane = tid & 63, wid = tid >> 6;
    const int wrow = (wid >> 1) * 32, wcol = (wid & 1) * 32;
    const int lr = lane & 15, lg = lane >> 4;
    f32x4 acc[2][2];
    #pragma unroll
    for (int i = 0; i < 2; ++i)
        #pragma unroll
        for (int j = 0; j < 2; ++j) acc[i][j] = (f32x4){0.f, 0.f, 0.f, 0.f};

    for (int k0 = 0; k0 < 512; k0 += 64) {
        #pragma unroll
        for (int l = 0; l < 4; ++l) {
            int ch = tid + l * 256;
            int row = ch >> 4, sg = (ch & 15) * 4;
            float4 av = *reinterpret_cast<const float4*>(&X[(size_t)(t0 + row) * 512 + k0 + sg]);
            ushort4 h4, l4; split4(av, h4, l4);
            *reinterpret_cast<ushort4*>(&Ahi[row][sg]) = h4;
            *reinterpret_cast<ushort4*>(&Alo[row][sg]) = l4;
            float4 bv = *reinterpret_cast<const float4*>(&W[(size_t)(j0 + row) * 512 + k0 + sg]);
            split4(bv, h4, l4);
            *reinterpret_cast<ushort4*>(&Bhi[row][sg]) = h4;
            *reinterpret_cast<ushort4*>(&Blo[row][sg]) = l4;
        }
        __syncthreads();
        #pragma unroll
        for (int kh = 0; kh < 2; ++kh) {
            const int kb = kh * 32 + lg * 8;
            bf16x8 ah0 = LD8(Ahi, wrow + lr, kb),      ah1 = LD8(Ahi, wrow + 16 + lr, kb);
            bf16x8 al0 = LD8(Alo, wrow + lr, kb),      al1 = LD8(Alo, wrow + 16 + lr, kb);
            bf16x8 bh0 = LD8(Bhi, wcol + lr, kb),      bh1 = LD8(Bhi, wcol + 16 + lr, kb);
            bf16x8 bl0 = LD8(Blo, wcol + lr, kb),      bl1 = LD8(Blo, wcol + 16 + lr, kb);
            acc[0][0] = mm3(ah0, al0, bh0, bl0, acc[0][0]);
            acc[0][1] = mm3(ah0, al0, bh1, bl1, acc[0][1]);
            acc[1][0] = mm3(ah1, al1, bh0, bl0, acc[1][0]);
            acc[1][1] = mm3(ah1, al1, bh1, bl1, acc[1][1]);
        }
        __syncthreads();
    }
    const int which = j0 >> 9;
    const int h = (j0 & 511) >> 6;
    float* dst = (which == 0) ? Qh : ((which == 1) ? Kh : Vh);
    #pragma unroll
    for (int i = 0; i < 2; ++i)
        #pragma unroll
        for (int j = 0; j < 2; ++j)
            #pragma unroll
            for (int r = 0; r < 4; ++r) {
                int row = wrow + i * 16 + lg * 4 + r;
                int col = wcol + j * 16 + lr;             // = d
                dst[(size_t)(h * T_LEN + t0 + row) * HD + col] = acc[i][j][r] + bias[j0 + col];
            }
}

// ---------------------------------------------------------------------------
// Kernel 6: y = attn @ out_w^T + out_b. AT bf16 hi/lo; W split on the fly.
// ---------------------------------------------------------------------------
__global__ __launch_bounds__(256) void k_out_mfma(
    const unsigned short* __restrict__ AThi, const unsigned short* __restrict__ ATlo,
    const float* __restrict__ W, const float* __restrict__ bias,
    float* __restrict__ Y)
{
    const int j0 = blockIdx.x * 64;
    const int t0 = blockIdx.y * 64;
    __shared__ __align__(16) unsigned short Ahi[64][72], Alo[64][72],
                                            Bhi[64][72], Blo[64][72];
    const int tid = threadIdx.x, lane = tid & 63, wid = tid >> 6;
    const int wrow = (wid >> 1) * 32, wcol = (wid & 1) * 32;
    const int lr = lane & 15, lg = lane >> 4;
    f32x4 acc[2][2];
    #pragma unroll
    for (int i = 0; i < 2; ++i)
        #pragma unroll
        for (int j = 0; j < 2; ++j) acc[i][j] = (f32x4){0.f, 0.f, 0.f, 0.f};

    for (int k0 = 0; k0 < 512; k0 += 64) {
        #pragma unroll
        for (int l = 0; l < 2; ++l) {
            int ch = tid + l * 256;
            int row = ch >> 3, sg = (ch & 7) * 8;
            size_t ao = (size_t)(t0 + row) * 512 + k0 + sg;
            *reinterpret_cast<int4*>(&Ahi[row][sg]) = *reinterpret_cast<const int4*>(&AThi[ao]);
            *reinterpret_cast<int4*>(&Alo[row][sg]) = *reinterpret_cast<const int4*>(&ATlo[ao]);
        }
        #pragma unroll
        for (int l = 0; l < 4; ++l) {
            int ch = tid + l * 256;
            int row = ch >> 4, sg = (ch & 15) * 4;
            float4 bv = *reinterpret_cast<const float4*>(&W[(size_t)(j0 + row) * 512 + k0 + sg]);
            ushort4 h4, l4; split4(bv, h4, l4);
            *reinterpret_cast<ushort4*>(&Bhi[row][sg]) = h4;
            *reinterpret_cast<ushort4*>(&Blo[row][sg]) = l4;
        }
        __syncthreads();
        #pragma unroll
        for (int kh = 0; kh < 2; ++kh) {
            const int kb = kh * 32 + lg * 8;
            bf16x8 ah0 = LD8(Ahi, wrow + lr, kb),      ah1 = LD8(Ahi, wrow + 16 + lr, kb);
            bf16x8 al0 = LD8(Alo, wrow + lr, kb),      al1 = LD8(Alo, wrow + 16 + lr, kb);
            bf16x8 bh0 = LD8(Bhi, wcol + lr, kb),      bh1 = LD8(Bhi, wcol + 16 + lr, kb);
            bf16x8 bl0 = LD8(Blo, wcol + lr, kb),      bl1 = LD8(Blo, wcol + 16 + lr, kb);
            acc[0][0] = mm3(ah0, al0, bh0, bl0, acc[0][0]);
            acc[0][1] = mm3(ah0, al0, bh1, bl1, acc[0][1]);
            acc[1][0] = mm3(ah1, al1, bh0, bl0, acc[1][0]);
            acc[1][1] = mm3(ah1, al1, bh1, bl1, acc[1][1]);
        }
        __syncthreads();
    }
    #pragma unroll
    for (int i = 0; i < 2; ++i)
        #pragma unroll
        for (int j = 0; j < 2; ++j)
            #pragma unroll
            for (int r = 0; r < 4; ++r) {
                int row = wrow + i * 16 + lg * 4 + r;
                int col = wcol + j * 16 + lr;
                Y[(size_t)(t0 + row) * EMB + j0 + col] = acc[i][j][r] + bias[j0 + col];
            }
}

// ---------------------------------------------------------------------------
// Kernel 2: features. One block per (h,t); wave0 -> q, wave1 -> k.
// Emits qf/kf hi/lo [H][T][F] as packed u32 (coalesced). No transposes.
// ---------------------------------------------------------------------------
__global__ __launch_bounds__(128) void k_features(
    const float* __restrict__ Qh, const float* __restrict__ Kh,
    const float* __restrict__ poly_proj, const float* __restrict__ omega,
    unsigned short* __restrict__ qfhi, unsigned short* __restrict__ qflo,
    unsigned short* __restrict__ kfhi, unsigned short* __restrict__ kflo)
{
    const int ht = blockIdx.x;          // h*T + t
    const int h = ht >> 10;
    const int wid = threadIdx.x >> 6, lane = threadIdx.x & 63;
    const float* Z = (wid ? Kh : Qh) + (size_t)ht * HD;
    float z = Z[lane];
    float ss = z * z;
    #pragma unroll
    for (int off = 32; off; off >>= 1) ss += __shfl_xor(ss, off, 64);
    const float inv = 1.0f / fmaxf(sqrtf(ss), 1e-12f);
    __shared__ float zs[2][64];
    __shared__ float poly[2][32];
    __shared__ float prf[2][4];
    zs[wid][lane] = z * inv;
    __syncthreads();
    const float S_NODE = (float)(1.0 / 2.000001);  // matches numpy astype(f32)
    const float SQRT2S = sqrtf(2.0f * S_NODE);
    if (lane < 32) {
        float a = 0.0f;
        for (int d = 0; d < 64; ++d)
            a = fmaf(zs[wid][d], poly_proj[(h * 64 + d) * 32 + lane], a);
        poly[wid][lane] = a * a;
    } else if (lane < 36) {
        const int m = lane - 32;
        float a = 0.0f;
        for (int d = 0; d < 64; ++d)
            a = fmaf(zs[wid][d], omega[(h * 64 + d) * 4 + m], a);
        float arg = fminf(fmaxf(fmaf(a, SQRT2S, -S_NODE), -20.0f), 20.0f);
        prf[wid][m] = expf(arg) * 0.5f;   // / sqrt(M=4)
    }
    __syncthreads();
    const int f0 = lane * 2;
    float v0 = poly[wid][f0 >> 2] * prf[wid][f0 & 3];
    float v1 = poly[wid][(f0 + 1) >> 2] * prf[wid][(f0 + 1) & 3];
    unsigned short h0 = f2bf(v0), l0 = f2bf(v0 - bf2f(h0));
    unsigned short h1 = f2bf(v1), l1 = f2bf(v1 - bf2f(h1));
    unsigned hp = (unsigned)h0 | ((unsigned)h1 << 16);
    unsigned lp = (unsigned)l0 | ((unsigned)l1 << 16);
    size_t wi = (size_t)ht * FDIM + f0;
    if (wid == 0) {
        *reinterpret_cast<unsigned*>(&qfhi[wi]) = hp;
        *reinterpret_cast<unsigned*>(&qflo[wi]) = lp;
    } else {
        *reinterpret_cast<unsigned*>(&kfhi[wi]) = hp;
        *reinterpret_cast<unsigned*>(&kflo[wi]) = lp;
    }
}

// ---------------------------------------------------------------------------
// Kernel 3: per-chunk S_c[f][d] = sum_t kf[t][f]*v[t][d] via MFMA.
// kfT and Vt built in LDS (coalesced global reads, XOR-swizzled LDS stores).
// ---------------------------------------------------------------------------
__global__ __launch_bounds__(256) void k_chunk_kv(
    const unsigned short* __restrict__ kfhi, const unsigned short* __restrict__ kflo,
    const float* __restrict__ Vh,
    float* __restrict__ Sch, float* __restrict__ zch)
{
    const int b = blockIdx.x, h = b >> 4, c = b & 15;
    const int t0 = c * TC;
    const int tid = threadIdx.x, lane = tid & 63, wid = tid >> 6;
    const int wrow = (wid >> 1) * 64, wcol = (wid & 1) * 32;
    const int lr = lane & 15, lg = lane >> 4;
    __shared__ __align__(16) unsigned short Ahi[128][72], Alo[128][72],   // kfT
                                            Bhi[64][72],  Blo[64][72];    // Vt
    // stage kfT: read kf[t][f] coalesced, store transposed+swizzled
    #pragma unroll
    for (int l = 0; l < 4; ++l) {
        int ch = tid + l * 256;
        int t = ch >> 4, f8 = (ch & 15) * 8;
        int tb = t >> 3, tl = t & 7, m = f8 >> 3;
        size_t ko = (size_t)((h << 10) + t0 + t) * FDIM + f8;
        int4 hv = *reinterpret_cast<const int4*>(&kfhi[ko]);
        int4 lv = *reinterpret_cast<const int4*>(&kflo[ko]);
        const unsigned short* hp = reinterpret_cast<const unsigned short*>(&hv);
        const unsigned short* lp = reinterpret_cast<const unsigned short*>(&lv);
        int col = (((tb ^ (m & 7)) << 3) + tl);
        #pragma unroll
        for (int j = 0; j < 8; ++j) {
            Ahi[f8 + j][col] = hp[j];
            Alo[f8 + j][col] = lp[j];
        }
    }
    // stage Vt: read v[t][d] f32 coalesced, split+transpose+swizzle
    #pragma unroll
    for (int l = 0; l < 4; ++l) {
        int ch = tid + l * 256;
        int t = ch >> 4, d4 = (ch & 15) * 4;
        int tb = t >> 3, tl = t & 7;
        float4 vv = *reinterpret_cast<const float4*>(&Vh[(size_t)((h << 10) + t0 + t) * HD + d4]);
        float arr[4] = {vv.x, vv.y, vv.z, vv.w};
        #pragma unroll
        for (int j = 0; j < 4; ++j) {
            int row = d4 + j;
            int col = (((tb ^ ((row >> 3) & 7)) << 3) + tl);
            unsigned short hv2 = f2bf(arr[j]);
            Bhi[row][col] = hv2;
            Blo[row][col] = f2bf(arr[j] - bf2f(hv2));
        }
    }
    __syncthreads();
    f32x4 acc[4][2];
    #pragma unroll
    for (int i = 0; i < 4; ++i)
        #pragma unroll
        for (int j = 0; j < 2; ++j) acc[i][j] = (f32x4){0.f, 0.f, 0.f, 0.f};
    #pragma unroll
    for (int kh = 0; kh < 2; ++kh) {
        const int kb = kh * 32 + lg * 8, cb = kb >> 3;
        const int d0 = wcol + lr, d1 = wcol + 16 + lr;
        const int c0 = ((cb ^ ((d0 >> 3) & 7)) << 3), c1 = ((cb ^ ((d1 >> 3) & 7)) << 3);
        bf16x8 bh0 = *reinterpret_cast<const bf16x8*>(&Bhi[d0][c0]);
        bf16x8 bl0 = *reinterpret_cast<const bf16x8*>(&Blo[d0][c0]);
        bf16x8 bh1 = *reinterpret_cast<const bf16x8*>(&Bhi[d1][c1]);
        bf16x8 bl1 = *reinterpret_cast<const bf16x8*>(&Blo[d1][c1]);
        #pragma unroll
        for (int fi = 0; fi < 4; ++fi) {
            int fr = wrow + fi * 16 + lr;
            int ca = ((cb ^ ((fr >> 3) & 7)) << 3);
            bf16x8 ah = *reinterpret_cast<const bf16x8*>(&Ahi[fr][ca]);
            bf16x8 al = *reinterpret_cast<const bf16x8*>(&Alo[fr][ca]);
            acc[fi][0] = mm3(ah, al, bh0, bl0, acc[fi][0]);
            acc[fi][1] = mm3(ah, al, bh1, bl1, acc[fi][1]);
        }
    }
    if (tid < FDIM) {
        float s = 0.f;
        const int g = (tid >> 3) & 7;
        #pragma unroll
        for (int cb2 = 0; cb2 < 8; ++cb2) {
            int base = ((cb2 ^ g) << 3);
            #pragma unroll
            for (int e = 0; e < 8; ++e)
                s += bf2f(Ahi[tid][base + e]) + bf2f(Alo[tid][base + e]);
        }
        zch[(h * NC + c) * FDIM + tid] = s;
    }
    float* S = Sch + (size_t)(h * NC + c) * FDIM * HD;
    #pragma unroll
    for (int fi = 0; fi < 4; ++fi)
        #pragma unroll
        for (int dj = 0; dj < 2; ++dj)
            #pragma unroll
            for (int r = 0; r < 4; ++r) {
                int f = wrow + fi * 16 + lg * 4 + r;
                int d = wcol + dj * 16 + lr;
                S[f * HD + d] = acc[fi][dj][r];
            }
}

// ---------------------------------------------------------------------------
// Kernel 4: exclusive prefix over chunks — coalesced f32, one thread/chain.
// ---------------------------------------------------------------------------
__global__ __launch_bounds__(256) void k_prefix(
    const float* __restrict__ Sch, const float* __restrict__ zch,
    float* __restrict__ Spre, float* __restrict__ zpre)
{
    const int h = blockIdx.x >> 5;
    const int e = ((blockIdx.x & 31) << 8) + threadIdx.x;   // 0..8191
    const size_t base = (size_t)h * NC * FDIM * HD + e;
    float vals[NC];
    #pragma unroll
    for (int c = 0; c < NC; ++c) vals[c] = Sch[base + (size_t)c * FDIM * HD];
    float run = 0.0f;
    #pragma unroll
    for (int c = 0; c < NC; ++c) {
        Spre[base + (size_t)c * FDIM * HD] = run;
        run += vals[c];
    }
    if ((blockIdx.x & 31) == 0 && threadIdx.x < FDIM) {
        const int zb = h * NC * FDIM + threadIdx.x;
        float zv[NC];
        #pragma unroll
        for (int c = 0; c < NC; ++c) zv[c] = zch[zb + c * FDIM];
        float zr = 0.0f;
        #pragma unroll
        for (int c = 0; c < NC; ++c) { zpre[zb + c * FDIM] = zr; zr += zv[c]; }
    }
}

// ---------------------------------------------------------------------------
// Kernel 5: attention core, all-MFMA, 2 blocks per (h,chunk) (32 q-rows each).
//   phase1 (f-tiled): accA = Qf.Kf^T ; accC = Qf.Spre (SpreT built in LDS);
//                     accN = Qf.zpre via broadcast-B MFMA
//   phase2: mask, rowsum, masked A -> LDS hi/lo; stage Vt (LDS transpose)
//   phase3: accC += A.V ; epilogue: out = accC/nrm -> AT hi/lo [T][EMB]
// ---------------------------------------------------------------------------
__global__ __launch_bounds__(256) void k_attn_mfma(
    const unsigned short* __restrict__ qfhi, const unsigned short* __restrict__ qflo,
    const unsigned short* __restrict__ kfhi, const unsigned short* __restrict__ kflo,
    const float* __restrict__ Spre, const float* __restrict__ Vh,
    const float* __restrict__ zpre,
    unsigned short* __restrict__ AThi, unsigned short* __restrict__ ATlo)
{
    const int b = blockIdx.x;
    const int h = b >> 5, c = (b >> 1) & 15, half = b & 1;
    const int tc0 = c * TC;            // chunk col base
    const int tq0 = tc0 + half * 32;   // this block's q-row base
    const int tid = threadIdx.x, lane = tid & 63, wid = tid >> 6;
    const int wrow = (wid >> 1) * 16, wcol = (wid & 1) * 32;
    const int lr = lane & 15, lg = lane >> 4;

    __shared__ __align__(16) unsigned short T0[32][72], T1[32][72];  // qf -> A
    __shared__ __align__(16) unsigned short T2[64][72], T3[64][72];  // kf -> Vt
    __shared__ __align__(16) unsigned short T4[64][72], T5[64][72];  // SpreT
    __shared__ unsigned short zhi[FDIM], zlo[FDIM];
    __shared__ float nrm_part[2][32], nrm[32];

    if (tid < FDIM) {
        float zv = zpre[(h * NC + c) * FDIM + tid];
        unsigned short zh = f2bf(zv);
        zhi[tid] = zh; zlo[tid] = f2bf(zv - bf2f(zh));
    }

    f32x4 accA[2], accC[2], accN;
    accA[0] = accA[1] = accC[0] = accC[1] = accN = (f32x4){0.f, 0.f, 0.f, 0.f};

    for (int f0 = 0; f0 < FDIM; f0 += 64) {
        {   // qf: 32 rows
            int row = tid >> 3, sg = (tid & 7) * 8;
            size_t qo = (size_t)(h * T_LEN + tq0 + row) * FDIM + f0 + sg;
            *reinterpret_cast<int4*>(&T0[row][sg]) = *reinterpret_cast<const int4*>(&qfhi[qo]);
            *reinterpret_cast<int4*>(&T1[row][sg]) = *reinterpret_cast<const int4*>(&qflo[qo]);
        }
        #pragma unroll
        for (int l = 0; l < 2; ++l) {   // kf: 64 rows (full chunk)
            int ch = tid + l * 256;
            int row = ch >> 3, sg = (ch & 7) * 8;
            size_t ko = (size_t)(h * T_LEN + tc0 + row) * FDIM + f0 + sg;
            *reinterpret_cast<int4*>(&T2[row][sg]) = *reinterpret_cast<const int4*>(&kfhi[ko]);
            *reinterpret_cast<int4*>(&T3[row][sg]) = *reinterpret_cast<const int4*>(&kflo[ko]);
        }
        #pragma unroll
        for (int l = 0; l < 4; ++l) {   // SpreT: read [f][d] f32, transpose
            int ch = tid + l * 256;
            int f = ch >> 4, d4 = (ch & 15) * 4;
            int fb = f >> 3, fl = f & 7;
            float4 sv = *reinterpret_cast<const float4*>(
                &Spre[((size_t)((h * NC + c) * FDIM + f0 + f)) * HD + d4]);
            float arr[4] = {sv.x, sv.y, sv.z, sv.w};
            #pragma unroll
            for (int j = 0; j < 4; ++j) {
                int row = d4 + j;
                int col = (((fb ^ ((row >> 3) & 7)) << 3) + fl);
                unsigned short hv = f2bf(arr[j]);
                T4[row][col] = hv;
                T5[row][col] = f2bf(arr[j] - bf2f(hv));
            }
        }
        __syncthreads();
        #pragma unroll
        for (int kh = 0; kh < 2; ++kh) {
            const int kb = kh * 32 + lg * 8, cb = kb >> 3;
            bf16x8 qh = LD8(T0, wrow + lr, kb), ql = LD8(T1, wrow + lr, kb);
            bf16x8 kh0 = LD8(T2, wcol + lr, kb),      kh1 = LD8(T2, wcol + 16 + lr, kb);
            bf16x8 kl0 = LD8(T3, wcol + lr, kb),      kl1 = LD8(T3, wcol + 16 + lr, kb);
            const int d0 = wcol + lr, d1 = wcol + 16 + lr;
            const int c0 = ((cb ^ ((d0 >> 3) & 7)) << 3), c1 = ((cb ^ ((d1 >> 3) & 7)) << 3);
            bf16x8 sh0 = *reinterpret_cast<const bf16x8*>(&T4[d0][c0]);
            bf16x8 sl0 = *reinterpret_cast<const bf16x8*>(&T5[d0][c0]);
            bf16x8 sh1 = *reinterpret_cast<const bf16x8*>(&T4[d1][c1]);
            bf16x8 sl1 = *reinterpret_cast<const bf16x8*>(&T5[d1][c1]);
            accA[0] = mm3(qh, ql, kh0, kl0, accA[0]);
            accA[1] = mm3(qh, ql, kh1, kl1, accA[1]);
            accC[0] = mm3(qh, ql, sh0, sl0, accC[0]);
            accC[1] = mm3(qh, ql, sh1, sl1, accC[1]);
            bf16x8 zh8, zl8;
            #pragma unroll
            for (int j = 0; j < 8; ++j) {
                zh8[j] = (short)zhi[f0 + kb + j];
                zl8[j] = (short)zlo[f0 + kb + j];
            }
            accN = mm3(qh, ql, zh8, zl8, accN);
        }
        __syncthreads();
    }

    // phase 2: mask + rowsum + A -> T0/T1 ; Vt -> T2/T3
    #pragma unroll
    for (int r = 0; r < 4; ++r) {
        int rowl = wrow + lg * 4 + r;
        int rowc = half * 32 + rowl;     // chunk-relative row for causal mask
        float rs = 0.f;
        #pragma unroll
        for (int j = 0; j < 2; ++j) {
            int col = wcol + j * 16 + lr;
            float vA = (col <= rowc) ? accA[j][r] : 0.f;
            rs += vA;
            unsigned short hv = f2bf(vA);
            T0[rowl][col] = hv;
            T1[rowl][col] = f2bf(vA - bf2f(hv));
        }
        #pragma unroll
        for (int off = 1; off < 16; off <<= 1) rs += __shfl_xor(rs, off, 64);
        if (lr == 0) {
            if ((wid & 1) == 0) nrm_part[0][rowl] = rs + accN[r];
            else                nrm_part[1][rowl] = rs;
        }
    }
    #pragma unroll
    for (int l = 0; l < 4; ++l) {        // Vt from v f32 (transpose+swizzle)
        int ch = tid + l * 256;
        int t = ch >> 4, d4 = (ch & 15) * 4;
        int tb = t >> 3, tl = t & 7;
        float4 vv = *reinterpret_cast<const float4*>(&Vh[(size_t)(h * T_LEN + tc0 + t) * HD + d4]);
        float arr[4] = {vv.x, vv.y, vv.z, vv.w};
        #pragma unroll
        for (int j = 0; j < 4; ++j) {
            int row = d4 + j;
            int col = (((tb ^ ((row >> 3) & 7)) << 3) + tl);
            unsigned short hv = f2bf(arr[j]);
            T2[row][col] = hv;
            T3[row][col] = f2bf(arr[j] - bf2f(hv));
        }
    }
    __syncthreads();
    if (tid < 32) nrm[tid] = fmaxf(nrm_part[0][tid] + nrm_part[1][tid], 1e-6f);

    // phase 3: accC += A_masked @ V
    #pragma unroll
    for (int kh = 0; kh < 2; ++kh) {
        const int kb = kh * 32 + lg * 8, cb = kb >> 3;
        bf16x8 ah = LD8(T0, wrow + lr, kb), al = LD8(T1, wrow + lr, kb);
        const int d0 = wcol + lr, d1 = wcol + 16 + lr;
        const int c0 = ((cb ^ ((d0 >> 3) & 7)) << 3), c1 = ((cb ^ ((d1 >> 3) & 7)) << 3);
        bf16x8 vh0 = *reinterpret_cast<const bf16x8*>(&T2[d0][c0]);
        bf16x8 vl0 = *reinterpret_cast<const bf16x8*>(&T3[d0][c0]);
        bf16x8 vh1 = *reinterpret_cast<const bf16x8*>(&T2[d1][c1]);
        bf16x8 vl1 = *reinterpret_cast<const bf16x8*>(&T3[d1][c1]);
        accC[0] = mm3(ah, al, vh0, vl0, accC[0]);
        accC[1] = mm3(ah, al, vh1, vl1, accC[1]);
    }
    __syncthreads();

    #pragma unroll
    for (int j = 0; j < 2; ++j)
        #pragma unroll
        for (int r = 0; r < 4; ++r) {
            int rowl = wrow + lg * 4 + r;
            int col = wcol + j * 16 + lr;
            float o = accC[j][r] / nrm[rowl];
            unsigned short hv = f2bf(o);
            size_t oi = (size_t)(tq0 + rowl) * EMB + h * HD + col;
            AThi[oi] = hv; ATlo[oi] = f2bf(o - bf2f(hv));
        }
}

// ---------------------------------------------------------------------------
// Workspace (~23.2 MB). Overlays: AThi->q, ATlo->k (q,k dead after features).
// ---------------------------------------------------------------------------
extern "C" void kernel_launch(void* const* d_in, const int* in_sizes, int n_in,
                              void* d_out, int out_size, void* d_ws, size_t ws_size,
                              hipStream_t stream) {
    const float* x         = (const float*)d_in[0];
    const float* qkv_w     = (const float*)d_in[1];
    const float* qkv_b     = (const float*)d_in[2];
    const float* out_w     = (const float*)d_in[3];
    const float* out_b     = (const float*)d_in[4];
    const float* omega     = (const float*)d_in[5];
    const float* poly_proj = (const float*)d_in[6];
    float* out = (float*)d_out;

    float* ws = (float*)d_ws;
    float* q = ws;                                  // 524288 f32
    float* k = q + 524288;                          // 524288 f32
    float* v = k + 524288;                          // 524288 f32
    unsigned short* qfhi = (unsigned short*)(v + 524288);   // 1048576 u16 each
    unsigned short* qflo = qfhi + 1048576;
    unsigned short* kfhi = qflo + 1048576;
    unsigned short* kflo = kfhi + 1048576;
    float* Sch  = (float*)(kflo + 1048576);         // 1048576 f32
    float* Spre = Sch + 1048576;                    // 1048576 f32
    float* zch  = Spre + 1048576;                   // 16384
    float* zpre = zch + 16384;                      // 16384
    unsigned short* AThi = (unsigned short*)q;      // overlay
    unsigned short* ATlo = (unsigned short*)k;      // overlay

    k_qkv_mfma<<<dim3(24, 16), 256, 0, stream>>>(x, qkv_w, qkv_b, q, k, v);
    k_features<<<NH * T_LEN, 128, 0, stream>>>(q, k, poly_proj, omega,
                                               qfhi, qflo, kfhi, kflo);
    k_chunk_kv<<<NH * NC, 256, 0, stream>>>(kfhi, kflo, v, Sch, zch);
    k_prefix<<<256, 256, 0, stream>>>(Sch, zch, Spre, zpre);
    k_attn_mfma<<<NH * NC * 2, 256, 0, stream>>>(qfhi, qflo, kfhi, kflo,
                                                 Spre, v, zpre, AThi, ATlo);
    k_out_mfma<<<dim3(8, 16), 256, 0, stream>>>(AThi, ATlo, out_w, out_b, out);
}

// Round 7
// 135.540 us; speedup vs baseline: 1.2237x; 1.0366x over previous
//
#include <hip/hip_runtime.h>

#define T_LEN 1024
#define EMB   512
#define NH    8
#define HD    64
#define PDIM  32
#define MDIM  4
#define FDIM  128   // PDIM*MDIM
#define TC    64    // chunk length
#define NC    16    // T_LEN/TC

typedef __attribute__((ext_vector_type(8))) short bf16x8;
typedef __attribute__((ext_vector_type(4))) float f32x4;

__device__ __forceinline__ unsigned short f2bf(float f) {
    unsigned u = __float_as_uint(f);
    unsigned r = u + 0x7fffu + ((u >> 16) & 1u);   // RNE
    return (unsigned short)(r >> 16);
}
__device__ __forceinline__ float bf2f(unsigned short h) {
    return __uint_as_float(((unsigned)h) << 16);
}
__device__ __forceinline__ void split4(float4 v, ushort4& h4, ushort4& l4) {
    h4.x = f2bf(v.x); l4.x = f2bf(v.x - bf2f(h4.x));
    h4.y = f2bf(v.y); l4.y = f2bf(v.y - bf2f(h4.y));
    h4.z = f2bf(v.z); l4.z = f2bf(v.z - bf2f(h4.z));
    h4.w = f2bf(v.w); l4.w = f2bf(v.w - bf2f(h4.w));
}
// split-bf16 product: (ah+al)*(bh+bl) ~= ah*bh + ah*bl + al*bh
__device__ __forceinline__ f32x4 mm3(bf16x8 ah, bf16x8 al, bf16x8 bh, bf16x8 bl, f32x4 acc) {
    acc = __builtin_amdgcn_mfma_f32_16x16x32_bf16(ah, bh, acc, 0, 0, 0);
    acc = __builtin_amdgcn_mfma_f32_16x16x32_bf16(ah, bl, acc, 0, 0, 0);
    acc = __builtin_amdgcn_mfma_f32_16x16x32_bf16(al, bh, acc, 0, 0, 0);
    return acc;
}
#define LD8(TILE, ROW, KB) (*reinterpret_cast<const bf16x8*>(&TILE[ROW][KB]))

// ---------------------------------------------------------------------------
// Kernel 1: qkv GEMM + FUSED features.
//  which==2 (v cols): write v f32 [H][T][D].
//  which==0/1 (q/k): normalize-after-projection: g=(z@[P|om])/||z||,
//  poly=g[0:32]^2, prf=exp(clip(g[32:36]*sqrt2s-s))*0.5, qf/kf[f=p*4+m]=poly_p*prf_m.
// ---------------------------------------------------------------------------
__global__ __launch_bounds__(256) void k_qkv_mfma(
    const float* __restrict__ X, const float* __restrict__ W,
    const float* __restrict__ bias,
    const float* __restrict__ poly_proj, const float* __restrict__ omega,
    float* __restrict__ Vh,
    unsigned short* __restrict__ qfhi, unsigned short* __restrict__ qflo,
    unsigned short* __restrict__ kfhi, unsigned short* __restrict__ kflo)
{
    const int j0 = blockIdx.x * 64;   // N=1536
    const int t0 = blockIdx.y * 64;   // M=1024
    __shared__ __align__(16) unsigned short Ahi[64][80], Alo[64][80],
                                            Bhi[64][80], Blo[64][80];
    __shared__ float poly_s[64][33];
    __shared__ float prf_s[64][5];
    __shared__ float nrm2[2][64];
    const int tid = threadIdx.x, lane = tid & 63, wid = tid >> 6;
    const int wrow = (wid >> 1) * 32, wcol = (wid & 1) * 32;
    const int lr = lane & 15, lg = lane >> 4;
    f32x4 acc[2][2];
    #pragma unroll
    for (int i = 0; i < 2; ++i)
        #pragma unroll
        for (int j = 0; j < 2; ++j) acc[i][j] = (f32x4){0.f, 0.f, 0.f, 0.f};

    for (int k0 = 0; k0 < 512; k0 += 64) {
        #pragma unroll
        for (int l = 0; l < 4; ++l) {
            int ch = tid + l * 256;
            int row = ch >> 4, sg = (ch & 15) * 4;
            float4 av = *reinterpret_cast<const float4*>(&X[(size_t)(t0 + row) * 512 + k0 + sg]);
            ushort4 h4, l4; split4(av, h4, l4);
            *reinterpret_cast<ushort4*>(&Ahi[row][sg]) = h4;
            *reinterpret_cast<ushort4*>(&Alo[row][sg]) = l4;
            float4 bv = *reinterpret_cast<const float4*>(&W[(size_t)(j0 + row) * 512 + k0 + sg]);
            split4(bv, h4, l4);
            *reinterpret_cast<ushort4*>(&Bhi[row][sg]) = h4;
            *reinterpret_cast<ushort4*>(&Blo[row][sg]) = l4;
        }
        __syncthreads();
        #pragma unroll
        for (int kh = 0; kh < 2; ++kh) {
            const int kb = kh * 32 + lg * 8;
            bf16x8 ah0 = LD8(Ahi, wrow + lr, kb),      ah1 = LD8(Ahi, wrow + 16 + lr, kb);
            bf16x8 al0 = LD8(Alo, wrow + lr, kb),      al1 = LD8(Alo, wrow + 16 + lr, kb);
            bf16x8 bh0 = LD8(Bhi, wcol + lr, kb),      bh1 = LD8(Bhi, wcol + 16 + lr, kb);
            bf16x8 bl0 = LD8(Blo, wcol + lr, kb),      bl1 = LD8(Blo, wcol + 16 + lr, kb);
            acc[0][0] = mm3(ah0, al0, bh0, bl0, acc[0][0]);
            acc[0][1] = mm3(ah0, al0, bh1, bl1, acc[0][1]);
            acc[1][0] = mm3(ah1, al1, bh0, bl0, acc[1][0]);
            acc[1][1] = mm3(ah1, al1, bh1, bl1, acc[1][1]);
        }
        __syncthreads();
    }
    const int which = j0 >> 9;
    const int h = (j0 & 511) >> 6;

    if (which == 2) {   // plain v output
        #pragma unroll
        for (int i = 0; i < 2; ++i)
            #pragma unroll
            for (int j = 0; j < 2; ++j)
                #pragma unroll
                for (int r = 0; r < 4; ++r) {
                    int row = wrow + i * 16 + lg * 4 + r;
                    int col = wcol + j * 16 + lr;
                    Vh[(size_t)(h * T_LEN + t0 + row) * HD + col] = acc[i][j][r] + bias[j0 + col];
                }
        return;
    }

    // ---- fused features ----
    // 1) z (+bias) -> Ahi/Alo as bf16 hi/lo; per-row sumsq partials -> nrm2
    #pragma unroll
    for (int i = 0; i < 2; ++i) {
        #pragma unroll
        for (int r = 0; r < 4; ++r) {
            int row = wrow + i * 16 + lg * 4 + r;
            float ss = 0.f;
            #pragma unroll
            for (int j = 0; j < 2; ++j) {
                int col = wcol + j * 16 + lr;
                float zv = acc[i][j][r] + bias[j0 + col];
                ss = fmaf(zv, zv, ss);
                unsigned short hv = f2bf(zv);
                Ahi[row][col] = hv;
                Alo[row][col] = f2bf(zv - bf2f(hv));
            }
            ss += __shfl_xor(ss, 1, 64);
            ss += __shfl_xor(ss, 2, 64);
            ss += __shfl_xor(ss, 4, 64);
            ss += __shfl_xor(ss, 8, 64);
            if (lr == 0) nrm2[wid & 1][row] = ss;
        }
    }
    // 2) stage Bp = [P^T | om^T | 0pad] (48 x 64) into Bhi/Blo
    {
        const float* P = poly_proj + (size_t)h * 64 * 32;   // [d][p]
        int d = tid >> 2, p8 = (tid & 3) * 8;
        #pragma unroll
        for (int e = 0; e < 8; ++e) {
            float pv = P[d * 32 + p8 + e];
            unsigned short hv = f2bf(pv);
            Bhi[p8 + e][d] = hv;
            Blo[p8 + e][d] = f2bf(pv - bf2f(hv));
        }
        if (tid < 64) {
            const float* Om = omega + (size_t)h * 64 * 4;   // [d][m]
            float4 om = *reinterpret_cast<const float4*>(&Om[tid * 4]);
            float oa[4] = {om.x, om.y, om.z, om.w};
            #pragma unroll
            for (int m = 0; m < 4; ++m) {
                unsigned short hv = f2bf(oa[m]);
                Bhi[32 + m][tid] = hv;
                Blo[32 + m][tid] = f2bf(oa[m] - bf2f(hv));
            }
        }
        for (int rr = tid; rr < 12 * 64; rr += 256) {
            int row = 36 + (rr >> 6), dd = rr & 63;
            Bhi[row][dd] = 0; Blo[row][dd] = 0;
        }
    }
    __syncthreads();
    // 3) G = Z @ Bp : M=64 (wave m-slice 16), N=48, K=64
    const int mrow = wid * 16;
    f32x4 g[3];
    g[0] = g[1] = g[2] = (f32x4){0.f, 0.f, 0.f, 0.f};
    #pragma unroll
    for (int kh = 0; kh < 2; ++kh) {
        const int kb = kh * 32 + lg * 8;
        bf16x8 ah = LD8(Ahi, mrow + lr, kb), al = LD8(Alo, mrow + lr, kb);
        #pragma unroll
        for (int j = 0; j < 3; ++j) {
            bf16x8 bh = LD8(Bhi, j * 16 + lr, kb), bl = LD8(Blo, j * 16 + lr, kb);
            g[j] = mm3(ah, al, bh, bl, g[j]);
        }
    }
    // 4) normalize, poly/prf -> LDS (same-wave producer/consumer, no barrier)
    const float S_NODE = (float)(1.0 / 2.000001);
    const float SQRT2S = sqrtf(2.0f * S_NODE);
    #pragma unroll
    for (int r = 0; r < 4; ++r) {
        int row = mrow + lg * 4 + r;
        float rn = 1.0f / fmaxf(sqrtf(nrm2[0][row] + nrm2[1][row]), 1e-12f);
        #pragma unroll
        for (int j = 0; j < 3; ++j) {
            float gv = g[j][r] * rn;
            if (j < 2) poly_s[row][j * 16 + lr] = gv * gv;
            else if (lr < 4) {
                float arg = fminf(fmaxf(fmaf(gv, SQRT2S, -S_NODE), -20.0f), 20.0f);
                prf_s[row][lr] = expf(arg) * 0.5f;
            }
        }
    }
    // 5) outer product + split + write (each lane: one row-quarter, 32 f)
    {
        int row = mrow + (lane >> 2), fq = lane & 3;
        float pr[8], pf[4];
        #pragma unroll
        for (int e = 0; e < 8; ++e) pr[e] = poly_s[row][fq * 8 + e];
        #pragma unroll
        for (int m = 0; m < 4; ++m) pf[m] = prf_s[row][m];
        int4 hi4[4], lo4[4];
        unsigned short* hp = reinterpret_cast<unsigned short*>(hi4);
        unsigned short* lp = reinterpret_cast<unsigned short*>(lo4);
        #pragma unroll
        for (int e = 0; e < 8; ++e)
            #pragma unroll
            for (int m = 0; m < 4; ++m) {
                float val = pr[e] * pf[m];
                unsigned short hv = f2bf(val);
                hp[e * 4 + m] = hv;
                lp[e * 4 + m] = f2bf(val - bf2f(hv));
            }
        unsigned short* dhi = (which == 0) ? qfhi : kfhi;
        unsigned short* dlo = (which == 0) ? qflo : kflo;
        size_t base = (size_t)(h * T_LEN + t0 + row) * FDIM + fq * 32;
        #pragma unroll
        for (int s = 0; s < 4; ++s) {
            *reinterpret_cast<int4*>(&dhi[base + s * 8]) = hi4[s];
            *reinterpret_cast<int4*>(&dlo[base + s * 8]) = lo4[s];
        }
    }
}

// ---------------------------------------------------------------------------
// Kernel 6: y = attn @ out_w^T + out_b. AT bf16 hi/lo; W split on the fly.
// ---------------------------------------------------------------------------
__global__ __launch_bounds__(256) void k_out_mfma(
    const unsigned short* __restrict__ AThi, const unsigned short* __restrict__ ATlo,
    const float* __restrict__ W, const float* __restrict__ bias,
    float* __restrict__ Y)
{
    const int j0 = blockIdx.x * 64;
    const int t0 = blockIdx.y * 64;
    __shared__ __align__(16) unsigned short Ahi[64][80], Alo[64][80],
                                            Bhi[64][80], Blo[64][80];
    const int tid = threadIdx.x, lane = tid & 63, wid = tid >> 6;
    const int wrow = (wid >> 1) * 32, wcol = (wid & 1) * 32;
    const int lr = lane & 15, lg = lane >> 4;
    f32x4 acc[2][2];
    #pragma unroll
    for (int i = 0; i < 2; ++i)
        #pragma unroll
        for (int j = 0; j < 2; ++j) acc[i][j] = (f32x4){0.f, 0.f, 0.f, 0.f};

    for (int k0 = 0; k0 < 512; k0 += 64) {
        #pragma unroll
        for (int l = 0; l < 2; ++l) {
            int ch = tid + l * 256;
            int row = ch >> 3, sg = (ch & 7) * 8;
            size_t ao = (size_t)(t0 + row) * 512 + k0 + sg;
            *reinterpret_cast<int4*>(&Ahi[row][sg]) = *reinterpret_cast<const int4*>(&AThi[ao]);
            *reinterpret_cast<int4*>(&Alo[row][sg]) = *reinterpret_cast<const int4*>(&ATlo[ao]);
        }
        #pragma unroll
        for (int l = 0; l < 4; ++l) {
            int ch = tid + l * 256;
            int row = ch >> 4, sg = (ch & 15) * 4;
            float4 bv = *reinterpret_cast<const float4*>(&W[(size_t)(j0 + row) * 512 + k0 + sg]);
            ushort4 h4, l4; split4(bv, h4, l4);
            *reinterpret_cast<ushort4*>(&Bhi[row][sg]) = h4;
            *reinterpret_cast<ushort4*>(&Blo[row][sg]) = l4;
        }
        __syncthreads();
        #pragma unroll
        for (int kh = 0; kh < 2; ++kh) {
            const int kb = kh * 32 + lg * 8;
            bf16x8 ah0 = LD8(Ahi, wrow + lr, kb),      ah1 = LD8(Ahi, wrow + 16 + lr, kb);
            bf16x8 al0 = LD8(Alo, wrow + lr, kb),      al1 = LD8(Alo, wrow + 16 + lr, kb);
            bf16x8 bh0 = LD8(Bhi, wcol + lr, kb),      bh1 = LD8(Bhi, wcol + 16 + lr, kb);
            bf16x8 bl0 = LD8(Blo, wcol + lr, kb),      bl1 = LD8(Blo, wcol + 16 + lr, kb);
            acc[0][0] = mm3(ah0, al0, bh0, bl0, acc[0][0]);
            acc[0][1] = mm3(ah0, al0, bh1, bl1, acc[0][1]);
            acc[1][0] = mm3(ah1, al1, bh0, bl0, acc[1][0]);
            acc[1][1] = mm3(ah1, al1, bh1, bl1, acc[1][1]);
        }
        __syncthreads();
    }
    #pragma unroll
    for (int i = 0; i < 2; ++i)
        #pragma unroll
        for (int j = 0; j < 2; ++j)
            #pragma unroll
            for (int r = 0; r < 4; ++r) {
                int row = wrow + i * 16 + lg * 4 + r;
                int col = wcol + j * 16 + lr;
                Y[(size_t)(t0 + row) * EMB + j0 + col] = acc[i][j][r] + bias[j0 + col];
            }
}

// ---------------------------------------------------------------------------
// Kernel 3: per-chunk S_c[f][d] = sum_t kf[t][f]*v[t][d] via MFMA.
// 256 blocks: (h, c, f-half). kfT/Vt built in LDS with XOR swizzle.
// ---------------------------------------------------------------------------
__global__ __launch_bounds__(256) void k_chunk_kv(
    const unsigned short* __restrict__ kfhi, const unsigned short* __restrict__ kflo,
    const float* __restrict__ Vh,
    float* __restrict__ Sch, float* __restrict__ zch)
{
    const int b = blockIdx.x;
    const int fh = b & 1, hc = b >> 1, h = hc >> 4, c = hc & 15;
    const int t0 = c * TC;
    const int tid = threadIdx.x, lane = tid & 63, wid = tid >> 6;
    const int wrow = (wid >> 1) * 32, wcol = (wid & 1) * 32;
    const int lr = lane & 15, lg = lane >> 4;
    __shared__ __align__(16) unsigned short Ahi[64][80], Alo[64][80],   // kfT (64 f rows)
                                            Bhi[64][80], Blo[64][80];   // Vt
    #pragma unroll
    for (int l = 0; l < 2; ++l) {   // kfT: 512 int4 chunks
        int ch = tid + l * 256;
        int t = ch >> 3, f8 = (ch & 7) * 8;
        int tb = t >> 3, tl = t & 7, m = f8 >> 3;
        size_t ko = (size_t)((h << 10) + t0 + t) * FDIM + fh * 64 + f8;
        int4 hv = *reinterpret_cast<const int4*>(&kfhi[ko]);
        int4 lv = *reinterpret_cast<const int4*>(&kflo[ko]);
        const unsigned short* hp = reinterpret_cast<const unsigned short*>(&hv);
        const unsigned short* lp = reinterpret_cast<const unsigned short*>(&lv);
        int col = ((tb ^ m) << 3) + tl;
        #pragma unroll
        for (int j = 0; j < 8; ++j) {
            Ahi[f8 + j][col] = hp[j];
            Alo[f8 + j][col] = lp[j];
        }
    }
    #pragma unroll
    for (int l = 0; l < 4; ++l) {   // Vt from v f32
        int ch = tid + l * 256;
        int t = ch >> 4, d4 = (ch & 15) * 4;
        int tb = t >> 3, tl = t & 7;
        float4 vv = *reinterpret_cast<const float4*>(&Vh[(size_t)((h << 10) + t0 + t) * HD + d4]);
        float arr[4] = {vv.x, vv.y, vv.z, vv.w};
        #pragma unroll
        for (int j = 0; j < 4; ++j) {
            int row = d4 + j;
            int col = ((tb ^ ((row >> 3) & 7)) << 3) + tl;
            unsigned short hv2 = f2bf(arr[j]);
            Bhi[row][col] = hv2;
            Blo[row][col] = f2bf(arr[j] - bf2f(hv2));
        }
    }
    __syncthreads();
    f32x4 acc[2][2];
    #pragma unroll
    for (int i = 0; i < 2; ++i)
        #pragma unroll
        for (int j = 0; j < 2; ++j) acc[i][j] = (f32x4){0.f, 0.f, 0.f, 0.f};
    #pragma unroll
    for (int kh = 0; kh < 2; ++kh) {
        const int kb = kh * 32 + lg * 8, cb = kb >> 3;
        const int d0 = wcol + lr, d1 = wcol + 16 + lr;
        const int c0 = ((cb ^ ((d0 >> 3) & 7)) << 3), c1 = ((cb ^ ((d1 >> 3) & 7)) << 3);
        bf16x8 bh0 = *reinterpret_cast<const bf16x8*>(&Bhi[d0][c0]);
        bf16x8 bl0 = *reinterpret_cast<const bf16x8*>(&Blo[d0][c0]);
        bf16x8 bh1 = *reinterpret_cast<const bf16x8*>(&Bhi[d1][c1]);
        bf16x8 bl1 = *reinterpret_cast<const bf16x8*>(&Blo[d1][c1]);
        #pragma unroll
        for (int fi = 0; fi < 2; ++fi) {
            int fr = wrow + fi * 16 + lr;
            int ca = ((cb ^ ((fr >> 3) & 7)) << 3);
            bf16x8 ah = *reinterpret_cast<const bf16x8*>(&Ahi[fr][ca]);
            bf16x8 al = *reinterpret_cast<const bf16x8*>(&Alo[fr][ca]);
            acc[fi][0] = mm3(ah, al, bh0, bl0, acc[fi][0]);
            acc[fi][1] = mm3(ah, al, bh1, bl1, acc[fi][1]);
        }
    }
    if (tid < 64) {
        float s = 0.f;
        const int g = (tid >> 3) & 7;
        #pragma unroll
        for (int cb2 = 0; cb2 < 8; ++cb2) {
            int base = ((cb2 ^ g) << 3);
            #pragma unroll
            for (int e = 0; e < 8; ++e)
                s += bf2f(Ahi[tid][base + e]) + bf2f(Alo[tid][base + e]);
        }
        zch[(h * NC + c) * FDIM + fh * 64 + tid] = s;
    }
    float* S = Sch + (size_t)(h * NC + c) * FDIM * HD;
    #pragma unroll
    for (int fi = 0; fi < 2; ++fi)
        #pragma unroll
        for (int dj = 0; dj < 2; ++dj)
            #pragma unroll
            for (int r = 0; r < 4; ++r) {
                int f = fh * 64 + wrow + fi * 16 + lg * 4 + r;
                int d = wcol + dj * 16 + lr;
                S[f * HD + d] = acc[fi][dj][r];
            }
}

// ---------------------------------------------------------------------------
// Kernel 5: attention core with FUSED chunk-prefix (reads Sch/zch directly,
// accumulating over chunks cc<c during staging). 2 blocks per (h,chunk).
// ---------------------------------------------------------------------------
__global__ __launch_bounds__(256) void k_attn_mfma(
    const unsigned short* __restrict__ qfhi, const unsigned short* __restrict__ qflo,
    const unsigned short* __restrict__ kfhi, const unsigned short* __restrict__ kflo,
    const float* __restrict__ Sch, const float* __restrict__ Vh,
    const float* __restrict__ zch,
    unsigned short* __restrict__ AThi, unsigned short* __restrict__ ATlo)
{
    const int b = blockIdx.x;
    const int h = b >> 5, c = (b >> 1) & 15, half = b & 1;
    const int tc0 = c * TC;
    const int tq0 = tc0 + half * 32;
    const int tid = threadIdx.x, lane = tid & 63, wid = tid >> 6;
    const int wrow = (wid >> 1) * 16, wcol = (wid & 1) * 32;
    const int lr = lane & 15, lg = lane >> 4;

    __shared__ __align__(16) unsigned short T0[32][80], T1[32][80];  // qf -> A
    __shared__ __align__(16) unsigned short T2[64][80], T3[64][80];  // kf -> Vt
    __shared__ __align__(16) unsigned short T4[64][80], T5[64][80];  // SpreT
    __shared__ unsigned short zhi[FDIM], zlo[FDIM];
    __shared__ float nrm_part[2][32], nrm[32];

    if (tid < FDIM) {
        float zv = 0.f;
        for (int cc = 0; cc < c; ++cc) zv += zch[(h * NC + cc) * FDIM + tid];
        unsigned short zh = f2bf(zv);
        zhi[tid] = zh; zlo[tid] = f2bf(zv - bf2f(zh));
    }

    f32x4 accA[2], accC[2], accN;
    accA[0] = accA[1] = accC[0] = accC[1] = accN = (f32x4){0.f, 0.f, 0.f, 0.f};

    for (int f0 = 0; f0 < FDIM; f0 += 64) {
        {   // qf: 32 rows
            int row = tid >> 3, sg = (tid & 7) * 8;
            size_t qo = (size_t)(h * T_LEN + tq0 + row) * FDIM + f0 + sg;
            *reinterpret_cast<int4*>(&T0[row][sg]) = *reinterpret_cast<const int4*>(&qfhi[qo]);
            *reinterpret_cast<int4*>(&T1[row][sg]) = *reinterpret_cast<const int4*>(&qflo[qo]);
        }
        #pragma unroll
        for (int l = 0; l < 2; ++l) {   // kf: 64 rows
            int ch = tid + l * 256;
            int row = ch >> 3, sg = (ch & 7) * 8;
            size_t ko = (size_t)(h * T_LEN + tc0 + row) * FDIM + f0 + sg;
            *reinterpret_cast<int4*>(&T2[row][sg]) = *reinterpret_cast<const int4*>(&kfhi[ko]);
            *reinterpret_cast<int4*>(&T3[row][sg]) = *reinterpret_cast<const int4*>(&kflo[ko]);
        }
        #pragma unroll
        for (int l = 0; l < 4; ++l) {   // SpreT = prefix-sum of Sch, transposed
            int ch = tid + l * 256;
            int f = ch >> 4, d4 = (ch & 15) * 4;
            int fb = f >> 3, fl = f & 7;
            float4 sv = make_float4(0.f, 0.f, 0.f, 0.f);
            for (int cc = 0; cc < c; ++cc) {
                float4 t = *reinterpret_cast<const float4*>(
                    &Sch[((size_t)((h * NC + cc) * FDIM + f0 + f)) * HD + d4]);
                sv.x += t.x; sv.y += t.y; sv.z += t.z; sv.w += t.w;
            }
            float arr[4] = {sv.x, sv.y, sv.z, sv.w};
            #pragma unroll
            for (int j = 0; j < 4; ++j) {
                int row = d4 + j;
                int col = ((fb ^ ((row >> 3) & 7)) << 3) + fl;
                unsigned short hv = f2bf(arr[j]);
                T4[row][col] = hv;
                T5[row][col] = f2bf(arr[j] - bf2f(hv));
            }
        }
        __syncthreads();
        #pragma unroll
        for (int kh = 0; kh < 2; ++kh) {
            const int kb = kh * 32 + lg * 8, cb = kb >> 3;
            bf16x8 qh = LD8(T0, wrow + lr, kb), ql = LD8(T1, wrow + lr, kb);
            bf16x8 kh0 = LD8(T2, wcol + lr, kb),      kh1 = LD8(T2, wcol + 16 + lr, kb);
            bf16x8 kl0 = LD8(T3, wcol + lr, kb),      kl1 = LD8(T3, wcol + 16 + lr, kb);
            const int d0 = wcol + lr, d1 = wcol + 16 + lr;
            const int c0 = ((cb ^ ((d0 >> 3) & 7)) << 3), c1 = ((cb ^ ((d1 >> 3) & 7)) << 3);
            bf16x8 sh0 = *reinterpret_cast<const bf16x8*>(&T4[d0][c0]);
            bf16x8 sl0 = *reinterpret_cast<const bf16x8*>(&T5[d0][c0]);
            bf16x8 sh1 = *reinterpret_cast<const bf16x8*>(&T4[d1][c1]);
            bf16x8 sl1 = *reinterpret_cast<const bf16x8*>(&T5[d1][c1]);
            accA[0] = mm3(qh, ql, kh0, kl0, accA[0]);
            accA[1] = mm3(qh, ql, kh1, kl1, accA[1]);
            accC[0] = mm3(qh, ql, sh0, sl0, accC[0]);
            accC[1] = mm3(qh, ql, sh1, sl1, accC[1]);
            bf16x8 zh8, zl8;
            #pragma unroll
            for (int j = 0; j < 8; ++j) {
                zh8[j] = (short)zhi[f0 + kb + j];
                zl8[j] = (short)zlo[f0 + kb + j];
            }
            accN = mm3(qh, ql, zh8, zl8, accN);
        }
        __syncthreads();
    }

    // phase 2: mask + rowsum + A -> T0/T1 ; Vt -> T2/T3
    #pragma unroll
    for (int r = 0; r < 4; ++r) {
        int rowl = wrow + lg * 4 + r;
        int rowc = half * 32 + rowl;
        float rs = 0.f;
        #pragma unroll
        for (int j = 0; j < 2; ++j) {
            int col = wcol + j * 16 + lr;
            float vA = (col <= rowc) ? accA[j][r] : 0.f;
            rs += vA;
            unsigned short hv = f2bf(vA);
            T0[rowl][col] = hv;
            T1[rowl][col] = f2bf(vA - bf2f(hv));
        }
        #pragma unroll
        for (int off = 1; off < 16; off <<= 1) rs += __shfl_xor(rs, off, 64);
        if (lr == 0) {
            if ((wid & 1) == 0) nrm_part[0][rowl] = rs + accN[r];
            else                nrm_part[1][rowl] = rs;
        }
    }
    #pragma unroll
    for (int l = 0; l < 4; ++l) {
        int ch = tid + l * 256;
        int t = ch >> 4, d4 = (ch & 15) * 4;
        int tb = t >> 3, tl = t & 7;
        float4 vv = *reinterpret_cast<const float4*>(&Vh[(size_t)(h * T_LEN + tc0 + t) * HD + d4]);
        float arr[4] = {vv.x, vv.y, vv.z, vv.w};
        #pragma unroll
        for (int j = 0; j < 4; ++j) {
            int row = d4 + j;
            int col = ((tb ^ ((row >> 3) & 7)) << 3) + tl;
            unsigned short hv = f2bf(arr[j]);
            T2[row][col] = hv;
            T3[row][col] = f2bf(arr[j] - bf2f(hv));
        }
    }
    __syncthreads();
    if (tid < 32) nrm[tid] = fmaxf(nrm_part[0][tid] + nrm_part[1][tid], 1e-6f);

    // phase 3: accC += A_masked @ V
    #pragma unroll
    for (int kh = 0; kh < 2; ++kh) {
        const int kb = kh * 32 + lg * 8, cb = kb >> 3;
        bf16x8 ah = LD8(T0, wrow + lr, kb), al = LD8(T1, wrow + lr, kb);
        const int d0 = wcol + lr, d1 = wcol + 16 + lr;
        const int c0 = ((cb ^ ((d0 >> 3) & 7)) << 3), c1 = ((cb ^ ((d1 >> 3) & 7)) << 3);
        bf16x8 vh0 = *reinterpret_cast<const bf16x8*>(&T2[d0][c0]);
        bf16x8 vl0 = *reinterpret_cast<const bf16x8*>(&T3[d0][c0]);
        bf16x8 vh1 = *reinterpret_cast<const bf16x8*>(&T2[d1][c1]);
        bf16x8 vl1 = *reinterpret_cast<const bf16x8*>(&T3[d1][c1]);
        accC[0] = mm3(ah, al, vh0, vl0, accC[0]);
        accC[1] = mm3(ah, al, vh1, vl1, accC[1]);
    }
    __syncthreads();

    #pragma unroll
    for (int j = 0; j < 2; ++j)
        #pragma unroll
        for (int r = 0; r < 4; ++r) {
            int rowl = wrow + lg * 4 + r;
            int col = wcol + j * 16 + lr;
            float o = accC[j][r] / nrm[rowl];
            unsigned short hv = f2bf(o);
            size_t oi = (size_t)(tq0 + rowl) * EMB + h * HD + col;
            AThi[oi] = hv; ATlo[oi] = f2bf(o - bf2f(hv));
        }
}

// ---------------------------------------------------------------------------
// 4-kernel pipeline. Workspace ~16.1 MB, no overlays needed.
// ---------------------------------------------------------------------------
extern "C" void kernel_launch(void* const* d_in, const int* in_sizes, int n_in,
                              void* d_out, int out_size, void* d_ws, size_t ws_size,
                              hipStream_t stream) {
    const float* x         = (const float*)d_in[0];
    const float* qkv_w     = (const float*)d_in[1];
    const float* qkv_b     = (const float*)d_in[2];
    const float* out_w     = (const float*)d_in[3];
    const float* out_b     = (const float*)d_in[4];
    const float* omega     = (const float*)d_in[5];
    const float* poly_proj = (const float*)d_in[6];
    float* out = (float*)d_out;

    float* ws = (float*)d_ws;
    float* v = ws;                                          // 524288 f32
    unsigned short* qfhi = (unsigned short*)(v + 524288);   // 1048576 u16 each
    unsigned short* qflo = qfhi + 1048576;
    unsigned short* kfhi = qflo + 1048576;
    unsigned short* kflo = kfhi + 1048576;
    float* Sch  = (float*)(kflo + 1048576);                 // 1048576 f32
    float* zch  = Sch + 1048576;                            // 16384 f32
    unsigned short* AThi = (unsigned short*)(zch + 16384);  // 524288 u16 each
    unsigned short* ATlo = AThi + 524288;

    k_qkv_mfma<<<dim3(24, 16), 256, 0, stream>>>(x, qkv_w, qkv_b, poly_proj, omega,
                                                 v, qfhi, qflo, kfhi, kflo);
    k_chunk_kv<<<256, 256, 0, stream>>>(kfhi, kflo, v, Sch, zch);
    k_attn_mfma<<<NH * NC * 2, 256, 0, stream>>>(qfhi, qflo, kfhi, kflo,
                                                 Sch, v, zch, AThi, ATlo);
    k_out_mfma<<<dim3(8, 16), 256, 0, stream>>>(AThi, ATlo, out_w, out_b, out);
}

// Round 8
// 112.157 us; speedup vs baseline: 1.4789x; 1.2085x over previous
//
#include <hip/hip_runtime.h>

#define T_LEN 1024
#define EMB   512
#define NH    8
#define HD    64
#define PDIM  32
#define MDIM  4
#define FDIM  128   // PDIM*MDIM
#define TC    64    // chunk length
#define NC    16    // T_LEN/TC

typedef __attribute__((ext_vector_type(8))) short bf16x8;
typedef __attribute__((ext_vector_type(4))) float f32x4;

__device__ __forceinline__ unsigned short f2bf(float f) {
    unsigned u = __float_as_uint(f);
    unsigned r = u + 0x7fffu + ((u >> 16) & 1u);   // RNE
    return (unsigned short)(r >> 16);
}
__device__ __forceinline__ float bf2f(unsigned short h) {
    return __uint_as_float(((unsigned)h) << 16);
}
__device__ __forceinline__ void split4(float4 v, ushort4& h4, ushort4& l4) {
    h4.x = f2bf(v.x); l4.x = f2bf(v.x - bf2f(h4.x));
    h4.y = f2bf(v.y); l4.y = f2bf(v.y - bf2f(h4.y));
    h4.z = f2bf(v.z); l4.z = f2bf(v.z - bf2f(h4.z));
    h4.w = f2bf(v.w); l4.w = f2bf(v.w - bf2f(h4.w));
}
// split-bf16 product: (ah+al)*(bh+bl) ~= ah*bh + ah*bl + al*bh
__device__ __forceinline__ f32x4 mm3(bf16x8 ah, bf16x8 al, bf16x8 bh, bf16x8 bl, f32x4 acc) {
    acc = __builtin_amdgcn_mfma_f32_16x16x32_bf16(ah, bh, acc, 0, 0, 0);
    acc = __builtin_amdgcn_mfma_f32_16x16x32_bf16(ah, bl, acc, 0, 0, 0);
    acc = __builtin_amdgcn_mfma_f32_16x16x32_bf16(al, bh, acc, 0, 0, 0);
    return acc;
}
#define LD8(TILE, ROW, KB) (*reinterpret_cast<const bf16x8*>(&TILE[ROW][KB]))

// ---------------------------------------------------------------------------
// Kernel 0: pre-split f32 -> bf16 hi/lo planes for x, qkv_w, out_w.
// ---------------------------------------------------------------------------
__global__ __launch_bounds__(256) void k_cvt(
    const float* __restrict__ X, const float* __restrict__ Wq,
    const float* __restrict__ Wo,
    unsigned short* __restrict__ Xhi, unsigned short* __restrict__ Xlo,
    unsigned short* __restrict__ Whi, unsigned short* __restrict__ Wlo,
    unsigned short* __restrict__ Ohi, unsigned short* __restrict__ Olo)
{
    int i = (blockIdx.x * 256 + threadIdx.x) * 4;
    const float* src; unsigned short *dh, *dl; int off;
    if (i < 524288)       { src = X;  dh = Xhi; dl = Xlo; off = i; }
    else if (i < 1310720) { src = Wq; dh = Whi; dl = Wlo; off = i - 524288; }
    else                  { src = Wo; dh = Ohi; dl = Olo; off = i - 1310720; }
    float4 v = *reinterpret_cast<const float4*>(&src[off]);
    ushort4 h4, l4; split4(v, h4, l4);
    *reinterpret_cast<ushort4*>(&dh[off]) = h4;
    *reinterpret_cast<ushort4*>(&dl[off]) = l4;
}

// ---------------------------------------------------------------------------
// Kernel 1: qkv GEMM (pre-split operands, pure int4 staging) + FUSED features.
//  which==2: v -> bf16 hi/lo planes [H][T][D] (coalesced).
//  which==0/1: g=(z@[P|om])/||z||, poly=g[0:32]^2,
//              prf=exp(clip(g[32:36]*sqrt2s-s))*0.5, qf/kf[f=p*4+m]=poly_p*prf_m.
// ---------------------------------------------------------------------------
__global__ __launch_bounds__(256) void k_qkv_mfma(
    const unsigned short* __restrict__ Xhi, const unsigned short* __restrict__ Xlo,
    const unsigned short* __restrict__ Whi, const unsigned short* __restrict__ Wlo,
    const float* __restrict__ bias,
    const float* __restrict__ poly_proj, const float* __restrict__ omega,
    unsigned short* __restrict__ Vhi, unsigned short* __restrict__ Vlo,
    unsigned short* __restrict__ qfhi, unsigned short* __restrict__ qflo,
    unsigned short* __restrict__ kfhi, unsigned short* __restrict__ kflo)
{
    const int j0 = blockIdx.x * 64;   // N=1536
    const int t0 = blockIdx.y * 64;   // M=1024
    __shared__ __align__(16) unsigned short Ahi[64][80], Alo[64][80],
                                            Bhi[64][80], Blo[64][80];
    __shared__ float poly_s[64][33];
    __shared__ float prf_s[64][5];
    __shared__ float nrm2[2][64];
    const int tid = threadIdx.x, lane = tid & 63, wid = tid >> 6;
    const int wrow = (wid >> 1) * 32, wcol = (wid & 1) * 32;
    const int lr = lane & 15, lg = lane >> 4;
    f32x4 acc[2][2];
    #pragma unroll
    for (int i = 0; i < 2; ++i)
        #pragma unroll
        for (int j = 0; j < 2; ++j) acc[i][j] = (f32x4){0.f, 0.f, 0.f, 0.f};

    for (int k0 = 0; k0 < 512; k0 += 64) {
        #pragma unroll
        for (int l = 0; l < 2; ++l) {
            int ch = tid + l * 256;
            int row = ch >> 3, sg = (ch & 7) * 8;
            size_t ao = (size_t)(t0 + row) * 512 + k0 + sg;
            size_t bo = (size_t)(j0 + row) * 512 + k0 + sg;
            *reinterpret_cast<int4*>(&Ahi[row][sg]) = *reinterpret_cast<const int4*>(&Xhi[ao]);
            *reinterpret_cast<int4*>(&Alo[row][sg]) = *reinterpret_cast<const int4*>(&Xlo[ao]);
            *reinterpret_cast<int4*>(&Bhi[row][sg]) = *reinterpret_cast<const int4*>(&Whi[bo]);
            *reinterpret_cast<int4*>(&Blo[row][sg]) = *reinterpret_cast<const int4*>(&Wlo[bo]);
        }
        __syncthreads();
        #pragma unroll
        for (int kh = 0; kh < 2; ++kh) {
            const int kb = kh * 32 + lg * 8;
            bf16x8 ah0 = LD8(Ahi, wrow + lr, kb),      ah1 = LD8(Ahi, wrow + 16 + lr, kb);
            bf16x8 al0 = LD8(Alo, wrow + lr, kb),      al1 = LD8(Alo, wrow + 16 + lr, kb);
            bf16x8 bh0 = LD8(Bhi, wcol + lr, kb),      bh1 = LD8(Bhi, wcol + 16 + lr, kb);
            bf16x8 bl0 = LD8(Blo, wcol + lr, kb),      bl1 = LD8(Blo, wcol + 16 + lr, kb);
            acc[0][0] = mm3(ah0, al0, bh0, bl0, acc[0][0]);
            acc[0][1] = mm3(ah0, al0, bh1, bl1, acc[0][1]);
            acc[1][0] = mm3(ah1, al1, bh0, bl0, acc[1][0]);
            acc[1][1] = mm3(ah1, al1, bh1, bl1, acc[1][1]);
        }
        __syncthreads();
    }
    const int which = j0 >> 9;
    const int h = (j0 & 511) >> 6;

    if (which == 2) {   // v output as bf16 hi/lo planes (coalesced)
        #pragma unroll
        for (int i = 0; i < 2; ++i)
            #pragma unroll
            for (int j = 0; j < 2; ++j)
                #pragma unroll
                for (int r = 0; r < 4; ++r) {
                    int row = wrow + i * 16 + lg * 4 + r;
                    int col = wcol + j * 16 + lr;
                    float val = acc[i][j][r] + bias[j0 + col];
                    unsigned short hv = f2bf(val);
                    size_t vi = (size_t)(h * T_LEN + t0 + row) * HD + col;
                    Vhi[vi] = hv; Vlo[vi] = f2bf(val - bf2f(hv));
                }
        return;
    }

    // ---- fused features ----
    #pragma unroll
    for (int i = 0; i < 2; ++i) {
        #pragma unroll
        for (int r = 0; r < 4; ++r) {
            int row = wrow + i * 16 + lg * 4 + r;
            float ss = 0.f;
            #pragma unroll
            for (int j = 0; j < 2; ++j) {
                int col = wcol + j * 16 + lr;
                float zv = acc[i][j][r] + bias[j0 + col];
                ss = fmaf(zv, zv, ss);
                unsigned short hv = f2bf(zv);
                Ahi[row][col] = hv;
                Alo[row][col] = f2bf(zv - bf2f(hv));
            }
            ss += __shfl_xor(ss, 1, 64);
            ss += __shfl_xor(ss, 2, 64);
            ss += __shfl_xor(ss, 4, 64);
            ss += __shfl_xor(ss, 8, 64);
            if (lr == 0) nrm2[wid & 1][row] = ss;
        }
    }
    {   // Bp = [P^T | om^T | 0pad] (48 x 64)
        const float* P = poly_proj + (size_t)h * 64 * 32;   // [d][p]
        int d = tid >> 2, p8 = (tid & 3) * 8;
        #pragma unroll
        for (int e = 0; e < 8; ++e) {
            float pv = P[d * 32 + p8 + e];
            unsigned short hv = f2bf(pv);
            Bhi[p8 + e][d] = hv;
            Blo[p8 + e][d] = f2bf(pv - bf2f(hv));
        }
        if (tid < 64) {
            const float* Om = omega + (size_t)h * 64 * 4;   // [d][m]
            float4 om = *reinterpret_cast<const float4*>(&Om[tid * 4]);
            float oa[4] = {om.x, om.y, om.z, om.w};
            #pragma unroll
            for (int m = 0; m < 4; ++m) {
                unsigned short hv = f2bf(oa[m]);
                Bhi[32 + m][tid] = hv;
                Blo[32 + m][tid] = f2bf(oa[m] - bf2f(hv));
            }
        }
        for (int rr = tid; rr < 12 * 64; rr += 256) {
            int row = 36 + (rr >> 6), dd = rr & 63;
            Bhi[row][dd] = 0; Blo[row][dd] = 0;
        }
    }
    __syncthreads();
    const int mrow = wid * 16;
    f32x4 g[3];
    g[0] = g[1] = g[2] = (f32x4){0.f, 0.f, 0.f, 0.f};
    #pragma unroll
    for (int kh = 0; kh < 2; ++kh) {
        const int kb = kh * 32 + lg * 8;
        bf16x8 ah = LD8(Ahi, mrow + lr, kb), al = LD8(Alo, mrow + lr, kb);
        #pragma unroll
        for (int j = 0; j < 3; ++j) {
            bf16x8 bh = LD8(Bhi, j * 16 + lr, kb), bl = LD8(Blo, j * 16 + lr, kb);
            g[j] = mm3(ah, al, bh, bl, g[j]);
        }
    }
    const float S_NODE = (float)(1.0 / 2.000001);
    const float SQRT2S = sqrtf(2.0f * S_NODE);
    #pragma unroll
    for (int r = 0; r < 4; ++r) {
        int row = mrow + lg * 4 + r;
        float rn = 1.0f / fmaxf(sqrtf(nrm2[0][row] + nrm2[1][row]), 1e-12f);
        #pragma unroll
        for (int j = 0; j < 3; ++j) {
            float gv = g[j][r] * rn;
            if (j < 2) poly_s[row][j * 16 + lr] = gv * gv;
            else if (lr < 4) {
                float arg = fminf(fmaxf(fmaf(gv, SQRT2S, -S_NODE), -20.0f), 20.0f);
                prf_s[row][lr] = expf(arg) * 0.5f;
            }
        }
    }
    {
        int row = mrow + (lane >> 2), fq = lane & 3;
        float pr[8], pf[4];
        #pragma unroll
        for (int e = 0; e < 8; ++e) pr[e] = poly_s[row][fq * 8 + e];
        #pragma unroll
        for (int m = 0; m < 4; ++m) pf[m] = prf_s[row][m];
        int4 hi4[4], lo4[4];
        unsigned short* hp = reinterpret_cast<unsigned short*>(hi4);
        unsigned short* lp = reinterpret_cast<unsigned short*>(lo4);
        #pragma unroll
        for (int e = 0; e < 8; ++e)
            #pragma unroll
            for (int m = 0; m < 4; ++m) {
                float val = pr[e] * pf[m];
                unsigned short hv = f2bf(val);
                hp[e * 4 + m] = hv;
                lp[e * 4 + m] = f2bf(val - bf2f(hv));
            }
        unsigned short* dhi = (which == 0) ? qfhi : kfhi;
        unsigned short* dlo = (which == 0) ? qflo : kflo;
        size_t base = (size_t)(h * T_LEN + t0 + row) * FDIM + fq * 32;
        #pragma unroll
        for (int s = 0; s < 4; ++s) {
            *reinterpret_cast<int4*>(&dhi[base + s * 8]) = hi4[s];
            *reinterpret_cast<int4*>(&dlo[base + s * 8]) = lo4[s];
        }
    }
}

// ---------------------------------------------------------------------------
// Kernel 6: y = attn @ out_w^T + out_b. All operands pre-split: int4 staging.
// ---------------------------------------------------------------------------
__global__ __launch_bounds__(256) void k_out_mfma(
    const unsigned short* __restrict__ AThi, const unsigned short* __restrict__ ATlo,
    const unsigned short* __restrict__ Ohi, const unsigned short* __restrict__ Olo,
    const float* __restrict__ bias, float* __restrict__ Y)
{
    const int j0 = blockIdx.x * 64;
    const int t0 = blockIdx.y * 64;
    __shared__ __align__(16) unsigned short Ahi[64][80], Alo[64][80],
                                            Bhi[64][80], Blo[64][80];
    const int tid = threadIdx.x, lane = tid & 63, wid = tid >> 6;
    const int wrow = (wid >> 1) * 32, wcol = (wid & 1) * 32;
    const int lr = lane & 15, lg = lane >> 4;
    f32x4 acc[2][2];
    #pragma unroll
    for (int i = 0; i < 2; ++i)
        #pragma unroll
        for (int j = 0; j < 2; ++j) acc[i][j] = (f32x4){0.f, 0.f, 0.f, 0.f};

    for (int k0 = 0; k0 < 512; k0 += 64) {
        #pragma unroll
        for (int l = 0; l < 2; ++l) {
            int ch = tid + l * 256;
            int row = ch >> 3, sg = (ch & 7) * 8;
            size_t ao = (size_t)(t0 + row) * 512 + k0 + sg;
            size_t bo = (size_t)(j0 + row) * 512 + k0 + sg;
            *reinterpret_cast<int4*>(&Ahi[row][sg]) = *reinterpret_cast<const int4*>(&AThi[ao]);
            *reinterpret_cast<int4*>(&Alo[row][sg]) = *reinterpret_cast<const int4*>(&ATlo[ao]);
            *reinterpret_cast<int4*>(&Bhi[row][sg]) = *reinterpret_cast<const int4*>(&Ohi[bo]);
            *reinterpret_cast<int4*>(&Blo[row][sg]) = *reinterpret_cast<const int4*>(&Olo[bo]);
        }
        __syncthreads();
        #pragma unroll
        for (int kh = 0; kh < 2; ++kh) {
            const int kb = kh * 32 + lg * 8;
            bf16x8 ah0 = LD8(Ahi, wrow + lr, kb),      ah1 = LD8(Ahi, wrow + 16 + lr, kb);
            bf16x8 al0 = LD8(Alo, wrow + lr, kb),      al1 = LD8(Alo, wrow + 16 + lr, kb);
            bf16x8 bh0 = LD8(Bhi, wcol + lr, kb),      bh1 = LD8(Bhi, wcol + 16 + lr, kb);
            bf16x8 bl0 = LD8(Blo, wcol + lr, kb),      bl1 = LD8(Blo, wcol + 16 + lr, kb);
            acc[0][0] = mm3(ah0, al0, bh0, bl0, acc[0][0]);
            acc[0][1] = mm3(ah0, al0, bh1, bl1, acc[0][1]);
            acc[1][0] = mm3(ah1, al1, bh0, bl0, acc[1][0]);
            acc[1][1] = mm3(ah1, al1, bh1, bl1, acc[1][1]);
        }
        __syncthreads();
    }
    #pragma unroll
    for (int i = 0; i < 2; ++i)
        #pragma unroll
        for (int j = 0; j < 2; ++j)
            #pragma unroll
            for (int r = 0; r < 4; ++r) {
                int row = wrow + i * 16 + lg * 4 + r;
                int col = wcol + j * 16 + lr;
                Y[(size_t)(t0 + row) * EMB + j0 + col] = acc[i][j][r] + bias[j0 + col];
            }
}

// ---------------------------------------------------------------------------
// Kernel 3: per-chunk S_c[f][d] = sum_t kf[t][f]*v[t][d] via MFMA.
// 256 blocks: (h, c, f-half). kfT/Vt built in LDS with XOR swizzle, no split.
// ---------------------------------------------------------------------------
__global__ __launch_bounds__(256) void k_chunk_kv(
    const unsigned short* __restrict__ kfhi, const unsigned short* __restrict__ kflo,
    const unsigned short* __restrict__ Vhi, const unsigned short* __restrict__ Vlo,
    float* __restrict__ Sch, float* __restrict__ zch)
{
    const int b = blockIdx.x;
    const int fh = b & 1, hc = b >> 1, h = hc >> 4, c = hc & 15;
    const int t0 = c * TC;
    const int tid = threadIdx.x, lane = tid & 63, wid = tid >> 6;
    const int wrow = (wid >> 1) * 32, wcol = (wid & 1) * 32;
    const int lr = lane & 15, lg = lane >> 4;
    __shared__ __align__(16) unsigned short Ahi[64][80], Alo[64][80],   // kfT
                                            Bhi[64][80], Blo[64][80];   // Vt
    #pragma unroll
    for (int l = 0; l < 2; ++l) {   // kfT
        int ch = tid + l * 256;
        int t = ch >> 3, f8 = (ch & 7) * 8;
        int tb = t >> 3, tl = t & 7, m = f8 >> 3;
        size_t ko = (size_t)((h << 10) + t0 + t) * FDIM + fh * 64 + f8;
        int4 hv = *reinterpret_cast<const int4*>(&kfhi[ko]);
        int4 lv = *reinterpret_cast<const int4*>(&kflo[ko]);
        const unsigned short* hp = reinterpret_cast<const unsigned short*>(&hv);
        const unsigned short* lp = reinterpret_cast<const unsigned short*>(&lv);
        int col = ((tb ^ m) << 3) + tl;
        #pragma unroll
        for (int j = 0; j < 8; ++j) {
            Ahi[f8 + j][col] = hp[j];
            Alo[f8 + j][col] = lp[j];
        }
    }
    #pragma unroll
    for (int l = 0; l < 4; ++l) {   // Vt from u16 planes
        int ch = tid + l * 256;     // 0..1023
        int plane = ch >> 9, rem = ch & 511;
        int t = rem >> 3, d8 = (rem & 7) * 8;
        int tb = t >> 3, tl = t & 7;
        const unsigned short* src = plane ? Vlo : Vhi;
        int4 vv = *reinterpret_cast<const int4*>(&src[(size_t)((h << 10) + t0 + t) * HD + d8]);
        const unsigned short* vp = reinterpret_cast<const unsigned short*>(&vv);
        int col = ((tb ^ (d8 >> 3)) << 3) + tl;
        unsigned short (*dst)[80] = plane ? Blo : Bhi;
        #pragma unroll
        for (int j = 0; j < 8; ++j) dst[d8 + j][col] = vp[j];
    }
    __syncthreads();
    f32x4 acc[2][2];
    #pragma unroll
    for (int i = 0; i < 2; ++i)
        #pragma unroll
        for (int j = 0; j < 2; ++j) acc[i][j] = (f32x4){0.f, 0.f, 0.f, 0.f};
    #pragma unroll
    for (int kh = 0; kh < 2; ++kh) {
        const int kb = kh * 32 + lg * 8, cb = kb >> 3;
        const int d0 = wcol + lr, d1 = wcol + 16 + lr;
        const int c0 = ((cb ^ ((d0 >> 3) & 7)) << 3), c1 = ((cb ^ ((d1 >> 3) & 7)) << 3);
        bf16x8 bh0 = *reinterpret_cast<const bf16x8*>(&Bhi[d0][c0]);
        bf16x8 bl0 = *reinterpret_cast<const bf16x8*>(&Blo[d0][c0]);
        bf16x8 bh1 = *reinterpret_cast<const bf16x8*>(&Bhi[d1][c1]);
        bf16x8 bl1 = *reinterpret_cast<const bf16x8*>(&Blo[d1][c1]);
        #pragma unroll
        for (int fi = 0; fi < 2; ++fi) {
            int fr = wrow + fi * 16 + lr;
            int ca = ((cb ^ ((fr >> 3) & 7)) << 3);
            bf16x8 ah = *reinterpret_cast<const bf16x8*>(&Ahi[fr][ca]);
            bf16x8 al = *reinterpret_cast<const bf16x8*>(&Alo[fr][ca]);
            acc[fi][0] = mm3(ah, al, bh0, bl0, acc[fi][0]);
            acc[fi][1] = mm3(ah, al, bh1, bl1, acc[fi][1]);
        }
    }
    if (tid < 64) {
        float s = 0.f;
        const int g = (tid >> 3) & 7;
        #pragma unroll
        for (int cb2 = 0; cb2 < 8; ++cb2) {
            int base = ((cb2 ^ g) << 3);
            #pragma unroll
            for (int e = 0; e < 8; ++e)
                s += bf2f(Ahi[tid][base + e]) + bf2f(Alo[tid][base + e]);
        }
        zch[(h * NC + c) * FDIM + fh * 64 + tid] = s;
    }
    float* S = Sch + (size_t)(h * NC + c) * FDIM * HD;
    #pragma unroll
    for (int fi = 0; fi < 2; ++fi)
        #pragma unroll
        for (int dj = 0; dj < 2; ++dj)
            #pragma unroll
            for (int r = 0; r < 4; ++r) {
                int f = fh * 64 + wrow + fi * 16 + lg * 4 + r;
                int d = wcol + dj * 16 + lr;
                S[f * HD + d] = acc[fi][dj][r];
            }
}

// ---------------------------------------------------------------------------
// Kernel 4: exclusive prefix over chunks — coalesced f32, one thread/chain.
// ---------------------------------------------------------------------------
__global__ __launch_bounds__(256) void k_prefix(
    const float* __restrict__ Sch, const float* __restrict__ zch,
    float* __restrict__ Spre, float* __restrict__ zpre)
{
    const int h = blockIdx.x >> 5;
    const int e = ((blockIdx.x & 31) << 8) + threadIdx.x;   // 0..8191
    const size_t base = (size_t)h * NC * FDIM * HD + e;
    float vals[NC];
    #pragma unroll
    for (int c = 0; c < NC; ++c) vals[c] = Sch[base + (size_t)c * FDIM * HD];
    float run = 0.0f;
    #pragma unroll
    for (int c = 0; c < NC; ++c) {
        Spre[base + (size_t)c * FDIM * HD] = run;
        run += vals[c];
    }
    if ((blockIdx.x & 31) == 0 && threadIdx.x < FDIM) {
        const int zb = h * NC * FDIM + threadIdx.x;
        float zv[NC];
        #pragma unroll
        for (int c = 0; c < NC; ++c) zv[c] = zch[zb + c * FDIM];
        float zr = 0.0f;
        #pragma unroll
        for (int c = 0; c < NC; ++c) { zpre[zb + c * FDIM] = zr; zr += zv[c]; }
    }
}

// ---------------------------------------------------------------------------
// Kernel 5: attention core. 2 blocks per (h,chunk), 32 q-rows each.
// ---------------------------------------------------------------------------
__global__ __launch_bounds__(256) void k_attn_mfma(
    const unsigned short* __restrict__ qfhi, const unsigned short* __restrict__ qflo,
    const unsigned short* __restrict__ kfhi, const unsigned short* __restrict__ kflo,
    const float* __restrict__ Spre,
    const unsigned short* __restrict__ Vhi, const unsigned short* __restrict__ Vlo,
    const float* __restrict__ zpre,
    unsigned short* __restrict__ AThi, unsigned short* __restrict__ ATlo)
{
    const int b = blockIdx.x;
    const int h = b >> 5, c = (b >> 1) & 15, half = b & 1;
    const int tc0 = c * TC;
    const int tq0 = tc0 + half * 32;
    const int tid = threadIdx.x, lane = tid & 63, wid = tid >> 6;
    const int wrow = (wid >> 1) * 16, wcol = (wid & 1) * 32;
    const int lr = lane & 15, lg = lane >> 4;

    __shared__ __align__(16) unsigned short T0[32][80], T1[32][80];  // qf -> A
    __shared__ __align__(16) unsigned short T2[64][80], T3[64][80];  // kf -> Vt
    __shared__ __align__(16) unsigned short T4[64][80], T5[64][80];  // SpreT
    __shared__ unsigned short zhi[FDIM], zlo[FDIM];
    __shared__ float nrm_part[2][32], nrm[32];

    if (tid < FDIM) {
        float zv = zpre[(h * NC + c) * FDIM + tid];
        unsigned short zh = f2bf(zv);
        zhi[tid] = zh; zlo[tid] = f2bf(zv - bf2f(zh));
    }

    f32x4 accA[2], accC[2], accN;
    accA[0] = accA[1] = accC[0] = accC[1] = accN = (f32x4){0.f, 0.f, 0.f, 0.f};

    for (int f0 = 0; f0 < FDIM; f0 += 64) {
        {   // qf: 32 rows
            int row = tid >> 3, sg = (tid & 7) * 8;
            size_t qo = (size_t)(h * T_LEN + tq0 + row) * FDIM + f0 + sg;
            *reinterpret_cast<int4*>(&T0[row][sg]) = *reinterpret_cast<const int4*>(&qfhi[qo]);
            *reinterpret_cast<int4*>(&T1[row][sg]) = *reinterpret_cast<const int4*>(&qflo[qo]);
        }
        #pragma unroll
        for (int l = 0; l < 2; ++l) {   // kf: 64 rows
            int ch = tid + l * 256;
            int row = ch >> 3, sg = (ch & 7) * 8;
            size_t ko = (size_t)(h * T_LEN + tc0 + row) * FDIM + f0 + sg;
            *reinterpret_cast<int4*>(&T2[row][sg]) = *reinterpret_cast<const int4*>(&kfhi[ko]);
            *reinterpret_cast<int4*>(&T3[row][sg]) = *reinterpret_cast<const int4*>(&kflo[ko]);
        }
        #pragma unroll
        for (int l = 0; l < 4; ++l) {   // SpreT: single read, transpose+split
            int ch = tid + l * 256;
            int f = ch >> 4, d4 = (ch & 15) * 4;
            int fb = f >> 3, fl = f & 7;
            float4 sv = *reinterpret_cast<const float4*>(
                &Spre[((size_t)((h * NC + c) * FDIM + f0 + f)) * HD + d4]);
            float arr[4] = {sv.x, sv.y, sv.z, sv.w};
            #pragma unroll
            for (int j = 0; j < 4; ++j) {
                int row = d4 + j;
                int col = ((fb ^ ((row >> 3) & 7)) << 3) + fl;
                unsigned short hv = f2bf(arr[j]);
                T4[row][col] = hv;
                T5[row][col] = f2bf(arr[j] - bf2f(hv));
            }
        }
        __syncthreads();
        #pragma unroll
        for (int kh = 0; kh < 2; ++kh) {
            const int kb = kh * 32 + lg * 8, cb = kb >> 3;
            bf16x8 qh = LD8(T0, wrow + lr, kb), ql = LD8(T1, wrow + lr, kb);
            bf16x8 kh0 = LD8(T2, wcol + lr, kb),      kh1 = LD8(T2, wcol + 16 + lr, kb);
            bf16x8 kl0 = LD8(T3, wcol + lr, kb),      kl1 = LD8(T3, wcol + 16 + lr, kb);
            const int d0 = wcol + lr, d1 = wcol + 16 + lr;
            const int c0 = ((cb ^ ((d0 >> 3) & 7)) << 3), c1 = ((cb ^ ((d1 >> 3) & 7)) << 3);
            bf16x8 sh0 = *reinterpret_cast<const bf16x8*>(&T4[d0][c0]);
            bf16x8 sl0 = *reinterpret_cast<const bf16x8*>(&T5[d0][c0]);
            bf16x8 sh1 = *reinterpret_cast<const bf16x8*>(&T4[d1][c1]);
            bf16x8 sl1 = *reinterpret_cast<const bf16x8*>(&T5[d1][c1]);
            accA[0] = mm3(qh, ql, kh0, kl0, accA[0]);
            accA[1] = mm3(qh, ql, kh1, kl1, accA[1]);
            accC[0] = mm3(qh, ql, sh0, sl0, accC[0]);
            accC[1] = mm3(qh, ql, sh1, sl1, accC[1]);
            bf16x8 zh8, zl8;
            #pragma unroll
            for (int j = 0; j < 8; ++j) {
                zh8[j] = (short)zhi[f0 + kb + j];
                zl8[j] = (short)zlo[f0 + kb + j];
            }
            accN = mm3(qh, ql, zh8, zl8, accN);
        }
        __syncthreads();
    }

    // phase 2: mask + rowsum + A -> T0/T1 ; Vt -> T2/T3
    #pragma unroll
    for (int r = 0; r < 4; ++r) {
        int rowl = wrow + lg * 4 + r;
        int rowc = half * 32 + rowl;
        float rs = 0.f;
        #pragma unroll
        for (int j = 0; j < 2; ++j) {
            int col = wcol + j * 16 + lr;
            float vA = (col <= rowc) ? accA[j][r] : 0.f;
            rs += vA;
            unsigned short hv = f2bf(vA);
            T0[rowl][col] = hv;
            T1[rowl][col] = f2bf(vA - bf2f(hv));
        }
        #pragma unroll
        for (int off = 1; off < 16; off <<= 1) rs += __shfl_xor(rs, off, 64);
        if (lr == 0) {
            if ((wid & 1) == 0) nrm_part[0][rowl] = rs + accN[r];
            else                nrm_part[1][rowl] = rs;
        }
    }
    #pragma unroll
    for (int l = 0; l < 4; ++l) {   // Vt from u16 planes
        int ch = tid + l * 256;
        int plane = ch >> 9, rem = ch & 511;
        int t = rem >> 3, d8 = (rem & 7) * 8;
        int tb = t >> 3, tl = t & 7;
        const unsigned short* src = plane ? Vlo : Vhi;
        int4 vv = *reinterpret_cast<const int4*>(&src[(size_t)(h * T_LEN + tc0 + t) * HD + d8]);
        const unsigned short* vp = reinterpret_cast<const unsigned short*>(&vv);
        int col = ((tb ^ (d8 >> 3)) << 3) + tl;
        unsigned short (*dst)[80] = plane ? T3 : T2;
        #pragma unroll
        for (int j = 0; j < 8; ++j) dst[d8 + j][col] = vp[j];
    }
    __syncthreads();
    if (tid < 32) nrm[tid] = fmaxf(nrm_part[0][tid] + nrm_part[1][tid], 1e-6f);

    // phase 3: accC += A_masked @ V
    #pragma unroll
    for (int kh = 0; kh < 2; ++kh) {
        const int kb = kh * 32 + lg * 8, cb = kb >> 3;
        bf16x8 ah = LD8(T0, wrow + lr, kb), al = LD8(T1, wrow + lr, kb);
        const int d0 = wcol + lr, d1 = wcol + 16 + lr;
        const int c0 = ((cb ^ ((d0 >> 3) & 7)) << 3), c1 = ((cb ^ ((d1 >> 3) & 7)) << 3);
        bf16x8 vh0 = *reinterpret_cast<const bf16x8*>(&T2[d0][c0]);
        bf16x8 vl0 = *reinterpret_cast<const bf16x8*>(&T3[d0][c0]);
        bf16x8 vh1 = *reinterpret_cast<const bf16x8*>(&T2[d1][c1]);
        bf16x8 vl1 = *reinterpret_cast<const bf16x8*>(&T3[d1][c1]);
        accC[0] = mm3(ah, al, vh0, vl0, accC[0]);
        accC[1] = mm3(ah, al, vh1, vl1, accC[1]);
    }
    __syncthreads();

    #pragma unroll
    for (int j = 0; j < 2; ++j)
        #pragma unroll
        for (int r = 0; r < 4; ++r) {
            int rowl = wrow + lg * 4 + r;
            int col = wcol + j * 16 + lr;
            float o = accC[j][r] / nrm[rowl];
            unsigned short hv = f2bf(o);
            size_t oi = (size_t)(tq0 + rowl) * EMB + h * HD + col;
            AThi[oi] = hv; ATlo[oi] = f2bf(o - bf2f(hv));
        }
}

// ---------------------------------------------------------------------------
// Workspace ~24.1 MB. Overlay: AThi/ATlo in Xhi/Xlo space
// (X planes read only by k_qkv; AT written by k_attn, read by k_out).
// ---------------------------------------------------------------------------
extern "C" void kernel_launch(void* const* d_in, const int* in_sizes, int n_in,
                              void* d_out, int out_size, void* d_ws, size_t ws_size,
                              hipStream_t stream) {
    const float* x         = (const float*)d_in[0];
    const float* qkv_w     = (const float*)d_in[1];
    const float* qkv_b     = (const float*)d_in[2];
    const float* out_w     = (const float*)d_in[3];
    const float* out_b     = (const float*)d_in[4];
    const float* omega     = (const float*)d_in[5];
    const float* poly_proj = (const float*)d_in[6];
    float* out = (float*)d_out;

    unsigned short* Xhi  = (unsigned short*)d_ws;           // 524288
    unsigned short* Xlo  = Xhi + 524288;
    unsigned short* Whi  = Xlo + 524288;                    // 786432
    unsigned short* Wlo  = Whi + 786432;
    unsigned short* Ohi  = Wlo + 786432;                    // 262144
    unsigned short* Olo  = Ohi + 262144;
    unsigned short* Vhi  = Olo + 262144;                    // 524288
    unsigned short* Vlo  = Vhi + 524288;
    unsigned short* qfhi = Vlo + 524288;                    // 1048576 each
    unsigned short* qflo = qfhi + 1048576;
    unsigned short* kfhi = qflo + 1048576;
    unsigned short* kflo = kfhi + 1048576;
    float* Sch  = (float*)(kflo + 1048576);                 // 1048576 f32
    float* Spre = Sch + 1048576;                            // 1048576 f32
    float* zch  = Spre + 1048576;                           // 16384
    float* zpre = zch + 16384;                              // 16384
    unsigned short* AThi = Xhi;                             // overlay
    unsigned short* ATlo = Xlo;                             // overlay

    k_cvt<<<1536, 256, 0, stream>>>(x, qkv_w, out_w, Xhi, Xlo, Whi, Wlo, Ohi, Olo);
    k_qkv_mfma<<<dim3(24, 16), 256, 0, stream>>>(Xhi, Xlo, Whi, Wlo, qkv_b,
                                                 poly_proj, omega, Vhi, Vlo,
                                                 qfhi, qflo, kfhi, kflo);
    k_chunk_kv<<<256, 256, 0, stream>>>(kfhi, kflo, Vhi, Vlo, Sch, zch);
    k_prefix<<<256, 256, 0, stream>>>(Sch, zch, Spre, zpre);
    k_attn_mfma<<<NH * NC * 2, 256, 0, stream>>>(qfhi, qflo, kfhi, kflo, Spre,
                                                 Vhi, Vlo, zpre, AThi, ATlo);
    k_out_mfma<<<dim3(8, 16), 256, 0, stream>>>(AThi, ATlo, Ohi, Olo, out_b, out);
}

// Round 9
// 110.983 us; speedup vs baseline: 1.4945x; 1.0106x over previous
//
#include <hip/hip_runtime.h>

#define T_LEN 1024
#define EMB   512
#define NH    8
#define HD    64
#define PDIM  32
#define MDIM  4
#define FDIM  128   // PDIM*MDIM
#define TC    64    // chunk length
#define NC    16    // T_LEN/TC

typedef __attribute__((ext_vector_type(8))) short bf16x8;
typedef __attribute__((ext_vector_type(4))) float f32x4;

__device__ __forceinline__ unsigned short f2bf(float f) {
    unsigned u = __float_as_uint(f);
    unsigned r = u + 0x7fffu + ((u >> 16) & 1u);   // RNE
    return (unsigned short)(r >> 16);
}
__device__ __forceinline__ float bf2f(unsigned short h) {
    return __uint_as_float(((unsigned)h) << 16);
}
__device__ __forceinline__ void split4(float4 v, ushort4& h4, ushort4& l4) {
    h4.x = f2bf(v.x); l4.x = f2bf(v.x - bf2f(h4.x));
    h4.y = f2bf(v.y); l4.y = f2bf(v.y - bf2f(h4.y));
    h4.z = f2bf(v.z); l4.z = f2bf(v.z - bf2f(h4.z));
    h4.w = f2bf(v.w); l4.w = f2bf(v.w - bf2f(h4.w));
}
// split-bf16 product: (ah+al)*(bh+bl) ~= ah*bh + ah*bl + al*bh
__device__ __forceinline__ f32x4 mm3(bf16x8 ah, bf16x8 al, bf16x8 bh, bf16x8 bl, f32x4 acc) {
    acc = __builtin_amdgcn_mfma_f32_16x16x32_bf16(ah, bh, acc, 0, 0, 0);
    acc = __builtin_amdgcn_mfma_f32_16x16x32_bf16(ah, bl, acc, 0, 0, 0);
    acc = __builtin_amdgcn_mfma_f32_16x16x32_bf16(al, bh, acc, 0, 0, 0);
    return acc;
}
#define LD8(TILE, ROW, KB) (*reinterpret_cast<const bf16x8*>(&TILE[ROW][KB]))

// ---------------------------------------------------------------------------
// Kernel 0: pre-split f32 -> bf16 hi/lo planes for x, qkv_w, out_w.
// ---------------------------------------------------------------------------
__global__ __launch_bounds__(256) void k_cvt(
    const float* __restrict__ X, const float* __restrict__ Wq,
    const float* __restrict__ Wo,
    unsigned short* __restrict__ Xhi, unsigned short* __restrict__ Xlo,
    unsigned short* __restrict__ Whi, unsigned short* __restrict__ Wlo,
    unsigned short* __restrict__ Ohi, unsigned short* __restrict__ Olo)
{
    int i = (blockIdx.x * 256 + threadIdx.x) * 4;
    const float* src; unsigned short *dh, *dl; int off;
    if (i < 524288)       { src = X;  dh = Xhi; dl = Xlo; off = i; }
    else if (i < 1310720) { src = Wq; dh = Whi; dl = Wlo; off = i - 524288; }
    else                  { src = Wo; dh = Ohi; dl = Olo; off = i - 1310720; }
    float4 v = *reinterpret_cast<const float4*>(&src[off]);
    ushort4 h4, l4; split4(v, h4, l4);
    *reinterpret_cast<ushort4*>(&dh[off]) = h4;
    *reinterpret_cast<ushort4*>(&dl[off]) = l4;
}

// ---------------------------------------------------------------------------
// Kernel 1: qkv GEMM (pre-split operands, pure int4 staging) + FUSED features.
// ---------------------------------------------------------------------------
__global__ __launch_bounds__(256) void k_qkv_mfma(
    const unsigned short* __restrict__ Xhi, const unsigned short* __restrict__ Xlo,
    const unsigned short* __restrict__ Whi, const unsigned short* __restrict__ Wlo,
    const float* __restrict__ bias,
    const float* __restrict__ poly_proj, const float* __restrict__ omega,
    unsigned short* __restrict__ Vhi, unsigned short* __restrict__ Vlo,
    unsigned short* __restrict__ qfhi, unsigned short* __restrict__ qflo,
    unsigned short* __restrict__ kfhi, unsigned short* __restrict__ kflo)
{
    const int j0 = blockIdx.x * 64;   // N=1536
    const int t0 = blockIdx.y * 64;   // M=1024
    __shared__ __align__(16) unsigned short Ahi[64][80], Alo[64][80],
                                            Bhi[64][80], Blo[64][80];
    __shared__ float poly_s[64][33];
    __shared__ float prf_s[64][5];
    __shared__ float nrm2[2][64];
    const int tid = threadIdx.x, lane = tid & 63, wid = tid >> 6;
    const int wrow = (wid >> 1) * 32, wcol = (wid & 1) * 32;
    const int lr = lane & 15, lg = lane >> 4;
    f32x4 acc[2][2];
    #pragma unroll
    for (int i = 0; i < 2; ++i)
        #pragma unroll
        for (int j = 0; j < 2; ++j) acc[i][j] = (f32x4){0.f, 0.f, 0.f, 0.f};

    for (int k0 = 0; k0 < 512; k0 += 64) {
        #pragma unroll
        for (int l = 0; l < 2; ++l) {
            int ch = tid + l * 256;
            int row = ch >> 3, sg = (ch & 7) * 8;
            size_t ao = (size_t)(t0 + row) * 512 + k0 + sg;
            size_t bo = (size_t)(j0 + row) * 512 + k0 + sg;
            *reinterpret_cast<int4*>(&Ahi[row][sg]) = *reinterpret_cast<const int4*>(&Xhi[ao]);
            *reinterpret_cast<int4*>(&Alo[row][sg]) = *reinterpret_cast<const int4*>(&Xlo[ao]);
            *reinterpret_cast<int4*>(&Bhi[row][sg]) = *reinterpret_cast<const int4*>(&Whi[bo]);
            *reinterpret_cast<int4*>(&Blo[row][sg]) = *reinterpret_cast<const int4*>(&Wlo[bo]);
        }
        __syncthreads();
        #pragma unroll
        for (int kh = 0; kh < 2; ++kh) {
            const int kb = kh * 32 + lg * 8;
            bf16x8 ah0 = LD8(Ahi, wrow + lr, kb),      ah1 = LD8(Ahi, wrow + 16 + lr, kb);
            bf16x8 al0 = LD8(Alo, wrow + lr, kb),      al1 = LD8(Alo, wrow + 16 + lr, kb);
            bf16x8 bh0 = LD8(Bhi, wcol + lr, kb),      bh1 = LD8(Bhi, wcol + 16 + lr, kb);
            bf16x8 bl0 = LD8(Blo, wcol + lr, kb),      bl1 = LD8(Blo, wcol + 16 + lr, kb);
            acc[0][0] = mm3(ah0, al0, bh0, bl0, acc[0][0]);
            acc[0][1] = mm3(ah0, al0, bh1, bl1, acc[0][1]);
            acc[1][0] = mm3(ah1, al1, bh0, bl0, acc[1][0]);
            acc[1][1] = mm3(ah1, al1, bh1, bl1, acc[1][1]);
        }
        __syncthreads();
    }
    const int which = j0 >> 9;
    const int h = (j0 & 511) >> 6;

    if (which == 2) {   // v output as bf16 hi/lo planes (coalesced)
        #pragma unroll
        for (int i = 0; i < 2; ++i)
            #pragma unroll
            for (int j = 0; j < 2; ++j)
                #pragma unroll
                for (int r = 0; r < 4; ++r) {
                    int row = wrow + i * 16 + lg * 4 + r;
                    int col = wcol + j * 16 + lr;
                    float val = acc[i][j][r] + bias[j0 + col];
                    unsigned short hv = f2bf(val);
                    size_t vi = (size_t)(h * T_LEN + t0 + row) * HD + col;
                    Vhi[vi] = hv; Vlo[vi] = f2bf(val - bf2f(hv));
                }
        return;
    }

    // ---- fused features ----
    #pragma unroll
    for (int i = 0; i < 2; ++i) {
        #pragma unroll
        for (int r = 0; r < 4; ++r) {
            int row = wrow + i * 16 + lg * 4 + r;
            float ss = 0.f;
            #pragma unroll
            for (int j = 0; j < 2; ++j) {
                int col = wcol + j * 16 + lr;
                float zv = acc[i][j][r] + bias[j0 + col];
                ss = fmaf(zv, zv, ss);
                unsigned short hv = f2bf(zv);
                Ahi[row][col] = hv;
                Alo[row][col] = f2bf(zv - bf2f(hv));
            }
            ss += __shfl_xor(ss, 1, 64);
            ss += __shfl_xor(ss, 2, 64);
            ss += __shfl_xor(ss, 4, 64);
            ss += __shfl_xor(ss, 8, 64);
            if (lr == 0) nrm2[wid & 1][row] = ss;
        }
    }
    {   // Bp = [P^T | om^T | 0pad] (48 x 64)
        const float* P = poly_proj + (size_t)h * 64 * 32;   // [d][p]
        int d = tid >> 2, p8 = (tid & 3) * 8;
        #pragma unroll
        for (int e = 0; e < 8; ++e) {
            float pv = P[d * 32 + p8 + e];
            unsigned short hv = f2bf(pv);
            Bhi[p8 + e][d] = hv;
            Blo[p8 + e][d] = f2bf(pv - bf2f(hv));
        }
        if (tid < 64) {
            const float* Om = omega + (size_t)h * 64 * 4;   // [d][m]
            float4 om = *reinterpret_cast<const float4*>(&Om[tid * 4]);
            float oa[4] = {om.x, om.y, om.z, om.w};
            #pragma unroll
            for (int m = 0; m < 4; ++m) {
                unsigned short hv = f2bf(oa[m]);
                Bhi[32 + m][tid] = hv;
                Blo[32 + m][tid] = f2bf(oa[m] - bf2f(hv));
            }
        }
        for (int rr = tid; rr < 12 * 64; rr += 256) {
            int row = 36 + (rr >> 6), dd = rr & 63;
            Bhi[row][dd] = 0; Blo[row][dd] = 0;
        }
    }
    __syncthreads();
    const int mrow = wid * 16;
    f32x4 g[3];
    g[0] = g[1] = g[2] = (f32x4){0.f, 0.f, 0.f, 0.f};
    #pragma unroll
    for (int kh = 0; kh < 2; ++kh) {
        const int kb = kh * 32 + lg * 8;
        bf16x8 ah = LD8(Ahi, mrow + lr, kb), al = LD8(Alo, mrow + lr, kb);
        #pragma unroll
        for (int j = 0; j < 3; ++j) {
            bf16x8 bh = LD8(Bhi, j * 16 + lr, kb), bl = LD8(Blo, j * 16 + lr, kb);
            g[j] = mm3(ah, al, bh, bl, g[j]);
        }
    }
    const float S_NODE = (float)(1.0 / 2.000001);
    const float SQRT2S = sqrtf(2.0f * S_NODE);
    #pragma unroll
    for (int r = 0; r < 4; ++r) {
        int row = mrow + lg * 4 + r;
        float rn = 1.0f / fmaxf(sqrtf(nrm2[0][row] + nrm2[1][row]), 1e-12f);
        #pragma unroll
        for (int j = 0; j < 3; ++j) {
            float gv = g[j][r] * rn;
            if (j < 2) poly_s[row][j * 16 + lr] = gv * gv;
            else if (lr < 4) {
                float arg = fminf(fmaxf(fmaf(gv, SQRT2S, -S_NODE), -20.0f), 20.0f);
                prf_s[row][lr] = expf(arg) * 0.5f;
            }
        }
    }
    {
        int row = mrow + (lane >> 2), fq = lane & 3;
        float pr[8], pf[4];
        #pragma unroll
        for (int e = 0; e < 8; ++e) pr[e] = poly_s[row][fq * 8 + e];
        #pragma unroll
        for (int m = 0; m < 4; ++m) pf[m] = prf_s[row][m];
        int4 hi4[4], lo4[4];
        unsigned short* hp = reinterpret_cast<unsigned short*>(hi4);
        unsigned short* lp = reinterpret_cast<unsigned short*>(lo4);
        #pragma unroll
        for (int e = 0; e < 8; ++e)
            #pragma unroll
            for (int m = 0; m < 4; ++m) {
                float val = pr[e] * pf[m];
                unsigned short hv = f2bf(val);
                hp[e * 4 + m] = hv;
                lp[e * 4 + m] = f2bf(val - bf2f(hv));
            }
        unsigned short* dhi = (which == 0) ? qfhi : kfhi;
        unsigned short* dlo = (which == 0) ? qflo : kflo;
        size_t base = (size_t)(h * T_LEN + t0 + row) * FDIM + fq * 32;
        #pragma unroll
        for (int s = 0; s < 4; ++s) {
            *reinterpret_cast<int4*>(&dhi[base + s * 8]) = hi4[s];
            *reinterpret_cast<int4*>(&dlo[base + s * 8]) = lo4[s];
        }
    }
}

// ---------------------------------------------------------------------------
// Kernel 6: y = attn @ out_w^T + out_b. All operands pre-split: int4 staging.
// ---------------------------------------------------------------------------
__global__ __launch_bounds__(256) void k_out_mfma(
    const unsigned short* __restrict__ AThi, const unsigned short* __restrict__ ATlo,
    const unsigned short* __restrict__ Ohi, const unsigned short* __restrict__ Olo,
    const float* __restrict__ bias, float* __restrict__ Y)
{
    const int j0 = blockIdx.x * 64;
    const int t0 = blockIdx.y * 64;
    __shared__ __align__(16) unsigned short Ahi[64][80], Alo[64][80],
                                            Bhi[64][80], Blo[64][80];
    const int tid = threadIdx.x, lane = tid & 63, wid = tid >> 6;
    const int wrow = (wid >> 1) * 32, wcol = (wid & 1) * 32;
    const int lr = lane & 15, lg = lane >> 4;
    f32x4 acc[2][2];
    #pragma unroll
    for (int i = 0; i < 2; ++i)
        #pragma unroll
        for (int j = 0; j < 2; ++j) acc[i][j] = (f32x4){0.f, 0.f, 0.f, 0.f};

    for (int k0 = 0; k0 < 512; k0 += 64) {
        #pragma unroll
        for (int l = 0; l < 2; ++l) {
            int ch = tid + l * 256;
            int row = ch >> 3, sg = (ch & 7) * 8;
            size_t ao = (size_t)(t0 + row) * 512 + k0 + sg;
            size_t bo = (size_t)(j0 + row) * 512 + k0 + sg;
            *reinterpret_cast<int4*>(&Ahi[row][sg]) = *reinterpret_cast<const int4*>(&AThi[ao]);
            *reinterpret_cast<int4*>(&Alo[row][sg]) = *reinterpret_cast<const int4*>(&ATlo[ao]);
            *reinterpret_cast<int4*>(&Bhi[row][sg]) = *reinterpret_cast<const int4*>(&Ohi[bo]);
            *reinterpret_cast<int4*>(&Blo[row][sg]) = *reinterpret_cast<const int4*>(&Olo[bo]);
        }
        __syncthreads();
        #pragma unroll
        for (int kh = 0; kh < 2; ++kh) {
            const int kb = kh * 32 + lg * 8;
            bf16x8 ah0 = LD8(Ahi, wrow + lr, kb),      ah1 = LD8(Ahi, wrow + 16 + lr, kb);
            bf16x8 al0 = LD8(Alo, wrow + lr, kb),      al1 = LD8(Alo, wrow + 16 + lr, kb);
            bf16x8 bh0 = LD8(Bhi, wcol + lr, kb),      bh1 = LD8(Bhi, wcol + 16 + lr, kb);
            bf16x8 bl0 = LD8(Blo, wcol + lr, kb),      bl1 = LD8(Blo, wcol + 16 + lr, kb);
            acc[0][0] = mm3(ah0, al0, bh0, bl0, acc[0][0]);
            acc[0][1] = mm3(ah0, al0, bh1, bl1, acc[0][1]);
            acc[1][0] = mm3(ah1, al1, bh0, bl0, acc[1][0]);
            acc[1][1] = mm3(ah1, al1, bh1, bl1, acc[1][1]);
        }
        __syncthreads();
    }
    #pragma unroll
    for (int i = 0; i < 2; ++i)
        #pragma unroll
        for (int j = 0; j < 2; ++j)
            #pragma unroll
            for (int r = 0; r < 4; ++r) {
                int row = wrow + i * 16 + lg * 4 + r;
                int col = wcol + j * 16 + lr;
                Y[(size_t)(t0 + row) * EMB + j0 + col] = acc[i][j][r] + bias[j0 + col];
            }
}

// ---------------------------------------------------------------------------
// Kernel 3: per-chunk SchT[d][f] = (V^T kf) via MFMA (operands swapped so the
// C-layout writes the TRANSPOSED state coalesced). Also dumps the Vt LDS tile
// to global planes (fh==0) for attn, and z column sums.
// ---------------------------------------------------------------------------
__global__ __launch_bounds__(256) void k_chunk_kv(
    const unsigned short* __restrict__ kfhi, const unsigned short* __restrict__ kflo,
    const unsigned short* __restrict__ Vhi, const unsigned short* __restrict__ Vlo,
    float* __restrict__ SchT, float* __restrict__ zch,
    unsigned short* __restrict__ Vthi, unsigned short* __restrict__ Vtlo)
{
    const int b = blockIdx.x;
    const int fh = b & 1, hc = b >> 1, h = hc >> 4, c = hc & 15;
    const int t0 = c * TC;
    const int tid = threadIdx.x, lane = tid & 63, wid = tid >> 6;
    const int wrow = (wid >> 1) * 32, wcol = (wid & 1) * 32;
    const int lr = lane & 15, lg = lane >> 4;
    __shared__ __align__(16) unsigned short Khi[64][80], Klo[64][80],   // kfT
                                            Ghi[64][80], Glo[64][80];   // Vt
    #pragma unroll
    for (int l = 0; l < 2; ++l) {   // kfT: transpose from kf (scalar stores, swizzled)
        int ch = tid + l * 256;
        int t = ch >> 3, f8 = (ch & 7) * 8;
        int tb = t >> 3, tl = t & 7, m = f8 >> 3;
        size_t ko = (size_t)((h << 10) + t0 + t) * FDIM + fh * 64 + f8;
        int4 hv = *reinterpret_cast<const int4*>(&kfhi[ko]);
        int4 lv = *reinterpret_cast<const int4*>(&kflo[ko]);
        const unsigned short* hp = reinterpret_cast<const unsigned short*>(&hv);
        const unsigned short* lp = reinterpret_cast<const unsigned short*>(&lv);
        int col = ((tb ^ m) << 3) + tl;
        #pragma unroll
        for (int j = 0; j < 8; ++j) {
            Khi[f8 + j][col] = hp[j];
            Klo[f8 + j][col] = lp[j];
        }
    }
    #pragma unroll
    for (int l = 0; l < 4; ++l) {   // Vt: transpose from V planes (swizzled)
        int ch = tid + l * 256;     // 0..1023
        int plane = ch >> 9, rem = ch & 511;
        int t = rem >> 3, d8 = (rem & 7) * 8;
        int tb = t >> 3, tl = t & 7;
        const unsigned short* src = plane ? Vlo : Vhi;
        int4 vv = *reinterpret_cast<const int4*>(&src[(size_t)((h << 10) + t0 + t) * HD + d8]);
        const unsigned short* vp = reinterpret_cast<const unsigned short*>(&vv);
        int col = ((tb ^ (d8 >> 3)) << 3) + tl;
        unsigned short (*dst)[80] = plane ? Glo : Ghi;
        #pragma unroll
        for (int j = 0; j < 8; ++j) dst[d8 + j][col] = vp[j];
    }
    __syncthreads();
    f32x4 acc[2][2];   // [d-frag][f-frag]
    #pragma unroll
    for (int i = 0; i < 2; ++i)
        #pragma unroll
        for (int j = 0; j < 2; ++j) acc[i][j] = (f32x4){0.f, 0.f, 0.f, 0.f};
    #pragma unroll
    for (int kh = 0; kh < 2; ++kh) {
        const int kb = kh * 32 + lg * 8, cb = kb >> 3;
        // B-op: kfT rows (f)
        const int f0r = wcol + lr, f1r = wcol + 16 + lr;
        const int c0 = ((cb ^ ((f0r >> 3) & 7)) << 3), c1 = ((cb ^ ((f1r >> 3) & 7)) << 3);
        bf16x8 bh0 = *reinterpret_cast<const bf16x8*>(&Khi[f0r][c0]);
        bf16x8 bl0 = *reinterpret_cast<const bf16x8*>(&Klo[f0r][c0]);
        bf16x8 bh1 = *reinterpret_cast<const bf16x8*>(&Khi[f1r][c1]);
        bf16x8 bl1 = *reinterpret_cast<const bf16x8*>(&Klo[f1r][c1]);
        // A-op: Vt rows (d)
        #pragma unroll
        for (int di = 0; di < 2; ++di) {
            int dr = wrow + di * 16 + lr;
            int ca = ((cb ^ ((dr >> 3) & 7)) << 3);
            bf16x8 ah = *reinterpret_cast<const bf16x8*>(&Ghi[dr][ca]);
            bf16x8 al = *reinterpret_cast<const bf16x8*>(&Glo[dr][ca]);
            acc[di][0] = mm3(ah, al, bh0, bl0, acc[di][0]);
            acc[di][1] = mm3(ah, al, bh1, bl1, acc[di][1]);
        }
    }
    if (tid < 64) {   // z column sums from kfT tile
        float s = 0.f;
        const int g = (tid >> 3) & 7;
        #pragma unroll
        for (int cb2 = 0; cb2 < 8; ++cb2) {
            int base = ((cb2 ^ g) << 3);
            #pragma unroll
            for (int e = 0; e < 8; ++e)
                s += bf2f(Khi[tid][base + e]) + bf2f(Klo[tid][base + e]);
        }
        zch[(h * NC + c) * FDIM + fh * 64 + tid] = s;
    }
    if (fh == 0) {   // dump Vt tile -> global planes [H][64d][1024t]
        #pragma unroll
        for (int l = 0; l < 4; ++l) {
            int ch = tid + l * 256;
            int plane = ch >> 9, rem = ch & 511;
            int d = rem >> 3, m = rem & 7;
            int g = (d >> 3) & 7;
            const unsigned short (*src)[80] = plane ? Glo : Ghi;
            unsigned short* dst = plane ? Vtlo : Vthi;
            *reinterpret_cast<int4*>(&dst[(size_t)(h * HD + d) * T_LEN + t0 + ((m ^ g) << 3)]) =
                *reinterpret_cast<const int4*>(&src[d][m << 3]);
        }
    }
    float* S = SchT + (size_t)(h * NC + c) * FDIM * HD;
    #pragma unroll
    for (int di = 0; di < 2; ++di)
        #pragma unroll
        for (int fj = 0; fj < 2; ++fj)
            #pragma unroll
            for (int r = 0; r < 4; ++r) {
                int d = wrow + di * 16 + lg * 4 + r;
                int f = fh * 64 + wcol + fj * 16 + lr;
                S[d * FDIM + f] = acc[di][fj][r];   // f in lane -> coalesced
            }
}

// ---------------------------------------------------------------------------
// Kernel 4: exclusive prefix over chunks on [d][f] layout; emits SpreT bf16
// hi/lo planes (packed u32 writes) + zpre f32. Fully coalesced.
// ---------------------------------------------------------------------------
__global__ __launch_bounds__(256) void k_prefix(
    const float* __restrict__ SchT, const float* __restrict__ zch,
    unsigned short* __restrict__ SThi, unsigned short* __restrict__ STlo,
    float* __restrict__ zpre)
{
    const int h = blockIdx.x >> 4;
    const int e = ((blockIdx.x & 15) << 9) + threadIdx.x * 2;   // 0..8190
    const size_t base = (size_t)h * NC * FDIM * HD + e;
    float2 vals[NC];
    #pragma unroll
    for (int c = 0; c < NC; ++c)
        vals[c] = *reinterpret_cast<const float2*>(&SchT[base + (size_t)c * FDIM * HD]);
    float r0 = 0.f, r1 = 0.f;
    #pragma unroll
    for (int c = 0; c < NC; ++c) {
        unsigned short h0 = f2bf(r0), h1 = f2bf(r1);
        unsigned short l0 = f2bf(r0 - bf2f(h0)), l1 = f2bf(r1 - bf2f(h1));
        size_t wi = base + (size_t)c * FDIM * HD;
        *reinterpret_cast<unsigned*>(&SThi[wi]) = (unsigned)h0 | ((unsigned)h1 << 16);
        *reinterpret_cast<unsigned*>(&STlo[wi]) = (unsigned)l0 | ((unsigned)l1 << 16);
        r0 += vals[c].x; r1 += vals[c].y;
    }
    if ((blockIdx.x & 15) == 0 && threadIdx.x < FDIM) {
        const int zb = h * NC * FDIM + threadIdx.x;
        float zv[NC];
        #pragma unroll
        for (int c = 0; c < NC; ++c) zv[c] = zch[zb + c * FDIM];
        float zr = 0.0f;
        #pragma unroll
        for (int c = 0; c < NC; ++c) { zpre[zb + c * FDIM] = zr; zr += zv[c]; }
    }
}

// ---------------------------------------------------------------------------
// Kernel 5: attention core. ALL staging is now pure int4 copies
// (SpreT and Vt arrive pre-transposed from chunk_kv/prefix).
// ---------------------------------------------------------------------------
__global__ __launch_bounds__(256) void k_attn_mfma(
    const unsigned short* __restrict__ qfhi, const unsigned short* __restrict__ qflo,
    const unsigned short* __restrict__ kfhi, const unsigned short* __restrict__ kflo,
    const unsigned short* __restrict__ SThi, const unsigned short* __restrict__ STlo,
    const unsigned short* __restrict__ Vthi, const unsigned short* __restrict__ Vtlo,
    const float* __restrict__ zpre,
    unsigned short* __restrict__ AThi, unsigned short* __restrict__ ATlo)
{
    const int b = blockIdx.x;
    const int h = b >> 5, c = (b >> 1) & 15, half = b & 1;
    const int tc0 = c * TC;
    const int tq0 = tc0 + half * 32;
    const int tid = threadIdx.x, lane = tid & 63, wid = tid >> 6;
    const int wrow = (wid >> 1) * 16, wcol = (wid & 1) * 32;
    const int lr = lane & 15, lg = lane >> 4;

    __shared__ __align__(16) unsigned short T0[32][80], T1[32][80];  // qf -> A
    __shared__ __align__(16) unsigned short T2[64][80], T3[64][80];  // kf -> Vt
    __shared__ __align__(16) unsigned short T4[64][80], T5[64][80];  // SpreT [d][f]
    __shared__ unsigned short zhi[FDIM], zlo[FDIM];
    __shared__ float nrm_part[2][32], nrm[32];

    if (tid < FDIM) {
        float zv = zpre[(h * NC + c) * FDIM + tid];
        unsigned short zh = f2bf(zv);
        zhi[tid] = zh; zlo[tid] = f2bf(zv - bf2f(zh));
    }

    f32x4 accA[2], accC[2], accN;
    accA[0] = accA[1] = accC[0] = accC[1] = accN = (f32x4){0.f, 0.f, 0.f, 0.f};

    for (int f0 = 0; f0 < FDIM; f0 += 64) {
        {   // qf: 32 rows
            int row = tid >> 3, sg = (tid & 7) * 8;
            size_t qo = (size_t)(h * T_LEN + tq0 + row) * FDIM + f0 + sg;
            *reinterpret_cast<int4*>(&T0[row][sg]) = *reinterpret_cast<const int4*>(&qfhi[qo]);
            *reinterpret_cast<int4*>(&T1[row][sg]) = *reinterpret_cast<const int4*>(&qflo[qo]);
        }
        #pragma unroll
        for (int l = 0; l < 2; ++l) {   // kf: 64 rows
            int ch = tid + l * 256;
            int row = ch >> 3, sg = (ch & 7) * 8;
            size_t ko = (size_t)(h * T_LEN + tc0 + row) * FDIM + f0 + sg;
            *reinterpret_cast<int4*>(&T2[row][sg]) = *reinterpret_cast<const int4*>(&kfhi[ko]);
            *reinterpret_cast<int4*>(&T3[row][sg]) = *reinterpret_cast<const int4*>(&kflo[ko]);
        }
        #pragma unroll
        for (int l = 0; l < 2; ++l) {   // SpreT [d][f-slice]: pure int4 copy
            int ch = tid + l * 256;
            int row = ch >> 3, sg = (ch & 7) * 8;
            size_t so = (size_t)(h * NC + c) * FDIM * HD + (size_t)row * FDIM + f0 + sg;
            *reinterpret_cast<int4*>(&T4[row][sg]) = *reinterpret_cast<const int4*>(&SThi[so]);
            *reinterpret_cast<int4*>(&T5[row][sg]) = *reinterpret_cast<const int4*>(&STlo[so]);
        }
        __syncthreads();
        #pragma unroll
        for (int kh = 0; kh < 2; ++kh) {
            const int kb = kh * 32 + lg * 8;
            bf16x8 qh = LD8(T0, wrow + lr, kb), ql = LD8(T1, wrow + lr, kb);
            bf16x8 kh0 = LD8(T2, wcol + lr, kb),      kh1 = LD8(T2, wcol + 16 + lr, kb);
            bf16x8 kl0 = LD8(T3, wcol + lr, kb),      kl1 = LD8(T3, wcol + 16 + lr, kb);
            bf16x8 sh0 = LD8(T4, wcol + lr, kb),      sh1 = LD8(T4, wcol + 16 + lr, kb);
            bf16x8 sl0 = LD8(T5, wcol + lr, kb),      sl1 = LD8(T5, wcol + 16 + lr, kb);
            accA[0] = mm3(qh, ql, kh0, kl0, accA[0]);
            accA[1] = mm3(qh, ql, kh1, kl1, accA[1]);
            accC[0] = mm3(qh, ql, sh0, sl0, accC[0]);
            accC[1] = mm3(qh, ql, sh1, sl1, accC[1]);
            bf16x8 zh8, zl8;
            #pragma unroll
            for (int j = 0; j < 8; ++j) {
                zh8[j] = (short)zhi[f0 + kb + j];
                zl8[j] = (short)zlo[f0 + kb + j];
            }
            accN = mm3(qh, ql, zh8, zl8, accN);
        }
        __syncthreads();
    }

    // phase 2: mask + rowsum + A -> T0/T1 ; Vt planes -> T2/T3 (int4 copies)
    #pragma unroll
    for (int r = 0; r < 4; ++r) {
        int rowl = wrow + lg * 4 + r;
        int rowc = half * 32 + rowl;
        float rs = 0.f;
        #pragma unroll
        for (int j = 0; j < 2; ++j) {
            int col = wcol + j * 16 + lr;
            float vA = (col <= rowc) ? accA[j][r] : 0.f;
            rs += vA;
            unsigned short hv = f2bf(vA);
            T0[rowl][col] = hv;
            T1[rowl][col] = f2bf(vA - bf2f(hv));
        }
        #pragma unroll
        for (int off = 1; off < 16; off <<= 1) rs += __shfl_xor(rs, off, 64);
        if (lr == 0) {
            if ((wid & 1) == 0) nrm_part[0][rowl] = rs + accN[r];
            else                nrm_part[1][rowl] = rs;
        }
    }
    #pragma unroll
    for (int l = 0; l < 4; ++l) {
        int ch = tid + l * 256;
        int plane = ch >> 9, rem = ch & 511;
        int row = rem >> 3, sg = (rem & 7) * 8;
        size_t vo = (size_t)(h * HD + row) * T_LEN + tc0 + sg;
        const unsigned short* src = plane ? Vtlo : Vthi;
        unsigned short (*dst)[80] = plane ? T3 : T2;
        *reinterpret_cast<int4*>(&dst[row][sg]) = *reinterpret_cast<const int4*>(&src[vo]);
    }
    __syncthreads();
    if (tid < 32) nrm[tid] = fmaxf(nrm_part[0][tid] + nrm_part[1][tid], 1e-6f);

    // phase 3: accC += A_masked @ V  (B-op = Vt [d][t], plain reads)
    #pragma unroll
    for (int kh = 0; kh < 2; ++kh) {
        const int kb = kh * 32 + lg * 8;
        bf16x8 ah = LD8(T0, wrow + lr, kb), al = LD8(T1, wrow + lr, kb);
        bf16x8 vh0 = LD8(T2, wcol + lr, kb),      vh1 = LD8(T2, wcol + 16 + lr, kb);
        bf16x8 vl0 = LD8(T3, wcol + lr, kb),      vl1 = LD8(T3, wcol + 16 + lr, kb);
        accC[0] = mm3(ah, al, vh0, vl0, accC[0]);
        accC[1] = mm3(ah, al, vh1, vl1, accC[1]);
    }
    __syncthreads();

    #pragma unroll
    for (int j = 0; j < 2; ++j)
        #pragma unroll
        for (int r = 0; r < 4; ++r) {
            int rowl = wrow + lg * 4 + r;
            int col = wcol + j * 16 + lr;
            float o = accC[j][r] / nrm[rowl];
            unsigned short hv = f2bf(o);
            size_t oi = (size_t)(tq0 + rowl) * EMB + h * HD + col;
            AThi[oi] = hv; ATlo[oi] = f2bf(o - bf2f(hv));
        }
}

// ---------------------------------------------------------------------------
// Workspace ~24.1 MB. Overlays (producer/consumer order audited):
//   AThi/ATlo in Xhi/Xlo  (X read only by k_qkv; AT written by k_attn)
//   Vthi/Vtlo in Whi/Wlo  (W read only by k_qkv; Vt written by k_chunk)
// ---------------------------------------------------------------------------
extern "C" void kernel_launch(void* const* d_in, const int* in_sizes, int n_in,
                              void* d_out, int out_size, void* d_ws, size_t ws_size,
                              hipStream_t stream) {
    const float* x         = (const float*)d_in[0];
    const float* qkv_w     = (const float*)d_in[1];
    const float* qkv_b     = (const float*)d_in[2];
    const float* out_w     = (const float*)d_in[3];
    const float* out_b     = (const float*)d_in[4];
    const float* omega     = (const float*)d_in[5];
    const float* poly_proj = (const float*)d_in[6];
    float* out = (float*)d_out;

    unsigned short* Xhi  = (unsigned short*)d_ws;           // 524288
    unsigned short* Xlo  = Xhi + 524288;
    unsigned short* Whi  = Xlo + 524288;                    // 786432
    unsigned short* Wlo  = Whi + 786432;
    unsigned short* Ohi  = Wlo + 786432;                    // 262144
    unsigned short* Olo  = Ohi + 262144;
    unsigned short* Vhi  = Olo + 262144;                    // 524288
    unsigned short* Vlo  = Vhi + 524288;
    unsigned short* qfhi = Vlo + 524288;                    // 1048576 each
    unsigned short* qflo = qfhi + 1048576;
    unsigned short* kfhi = qflo + 1048576;
    unsigned short* kflo = kfhi + 1048576;
    float* SchT = (float*)(kflo + 1048576);                 // 1048576 f32
    unsigned short* SThi = (unsigned short*)(SchT + 1048576); // 1048576 each
    unsigned short* STlo = SThi + 1048576;
    float* zch  = (float*)(STlo + 1048576);                 // 16384
    float* zpre = zch + 16384;                              // 16384
    unsigned short* AThi = Xhi;                             // overlay
    unsigned short* ATlo = Xlo;                             // overlay
    unsigned short* Vthi = Whi;                             // overlay (1MB in W's 3MB)
    unsigned short* Vtlo = Whi + 524288;                    // overlay

    k_cvt<<<1536, 256, 0, stream>>>(x, qkv_w, out_w, Xhi, Xlo, Whi, Wlo, Ohi, Olo);
    k_qkv_mfma<<<dim3(24, 16), 256, 0, stream>>>(Xhi, Xlo, Whi, Wlo, qkv_b,
                                                 poly_proj, omega, Vhi, Vlo,
                                                 qfhi, qflo, kfhi, kflo);
    k_chunk_kv<<<256, 256, 0, stream>>>(kfhi, kflo, Vhi, Vlo, SchT, zch, Vthi, Vtlo);
    k_prefix<<<128, 256, 0, stream>>>(SchT, zch, SThi, STlo, zpre);
    k_attn_mfma<<<NH * NC * 2, 256, 0, stream>>>(qfhi, qflo, kfhi, kflo, SThi, STlo,
                                                 Vthi, Vtlo, zpre, AThi, ATlo);
    k_out_mfma<<<dim3(8, 16), 256, 0, stream>>>(AThi, ATlo, Ohi, Olo, out_b, out);
}